// Round 10
// baseline (18553.127 us; speedup 1.0000x reference)
//
#include <hip/hip_runtime.h>

#define NB 36
#define NT 60

struct Params {
  const float *data;
  const float *W0, *b0, *W1, *b1, *W2, *b2, *Wf1, *bf1, *Wf2, *bf2;
  float *xb, *w0t, *w1t, *w2t;
  float *out0, *outp1, *outp2, *u1s;
  float *dm0, *dm1, *dmp1, *dm2, *dmp2, *dmh1, *dmh2;
  float *acc;
  float *zbase; int zn4;
};

__global__ void __launch_bounds__(256) k_prep(Params p){
  int gt  = blockIdx.x*256 + threadIdx.x;
  int STR = gridDim.x*256;
  if(gt < NB*11) p.acc[gt] = 0.f;
  for(int i=gt; i<p.zn4; i+=STR) ((float4*)p.zbase)[i] = make_float4(0.f,0.f,0.f,0.f);
  const int PLANE = 34*34;
  for(int i=gt; i<NT*NB*2*PLANE; i+=STR){
    int t   = i / (NB*2*PLANE);
    int rem = i % (NB*2*PLANE);
    int bc  = rem / PLANE;
    int pix = rem % PLANE;
    int ph = pix/34, pw = pix%34;
    float v = 0.f;
    if(ph>=1 && ph<=32 && pw>=1 && pw<=32){
      float d = p.data[((size_t)bc*1024 + (ph-1)*32 + (pw-1))*NT + t];
      v = (d > 1.0f) ? 1.0f : 0.0f;
    }
    p.xb[i] = v;
  }
  for(int i=gt; i<2*9*64; i+=STR){
    int co=i%64, rr=i/64; p.w0t[i] = p.W0[(co*2 + rr/9)*9 + rr%9];
  }
  for(int i=gt; i<64*9*128; i+=STR){
    int co=i%128, rr=i/128; p.w1t[i] = p.W1[(co*64 + rr/9)*9 + rr%9];
  }
  for(int i=gt; i<128*9*128; i+=STR){
    int co=i%128, rr=i/128; p.w2t[i] = p.W2[(co*128 + rr/9)*9 + rr%9];
  }
}

// ---------------- fused conv3x3 + LIAF (+ optional avgpool2 + LIAF) ----------------
// Halo-padded input (stride HW+2) -> no bounds checks. Weights in LDS, float4
// broadcast reads. Thread: tc=tid%(HW/WX) covers WX columns, ty rows group of
// PX rows, CO couts. Register-double-buffered input prefetch across cin.
// WX=2 && POOL: the 2x2 pool patch is thread-local (no shuffles/predication).
template<int Cin,int Cout,int HW,int CO,int PX,int WX,int TY,int POOL,int OPAD,int PPAD,int CS>
__global__ void __launch_bounds__((HW/WX)*TY)
k_conv(const float* __restrict__ x, const float* __restrict__ wt,
       const float* __restrict__ bias, float* __restrict__ dm,
       float* __restrict__ out, float* __restrict__ dmp, float* __restrict__ outp)
{
  const int NCOG = Cout/CO;
  const int TH   = PX*TY;
  const int NHG  = HW/TH;
  const int NH4  = CO/4;
  const int NTHL = (HW/WX)*TY;
  const int PIN  = HW+2;
  const int XR   = PX+2, XC = WX+2;
  int tile = blockIdx.x;
  int tid  = threadIdx.x;
  int cog = tile % NCOG;
  int hg  = (tile/NCOG) % NHG;
  int b   = tile/(NCOG*NHG);
  int tc  = tid % (HW/WX);
  int ty  = tid / (HW/WX);
  int w0  = tc*WX;
  int h0  = hg*TH + ty*PX;

  __shared__ __align__(16) float wl[CS*9*CO];

  float accs[PX][WX][CO];
  #pragma unroll
  for(int p=0;p<PX;p++)
    #pragma unroll
    for(int q=0;q<WX;q++)
      #pragma unroll
      for(int c=0;c<CO;c++) accs[p][q][c]=0.f;

  for(int cs=0; cs<Cin; cs+=CS){
    __syncthreads();
    for(int j=tid; j<CS*9*CO; j+=NTHL){
      int c  = j % CO;
      int rr = j / CO;
      wl[j] = wt[(cs*9 + rr)*Cout + cog*CO + c];
    }
    __syncthreads();

    float xv[XR][XC];
    {
      const float* xc = x + ((size_t)b*Cin + cs)*PIN*PIN + (size_t)h0*PIN + w0;
      #pragma unroll
      for(int r=0;r<XR;r++)
        #pragma unroll
        for(int c=0;c<XC;c++) xv[r][c] = xc[(size_t)r*PIN + c];
    }

    for(int lc=0; lc<CS; lc++){
      int lcn = (lc+1 < CS) ? lc+1 : lc;
      float nv[XR][XC];
      {
        const float* xc = x + ((size_t)b*Cin + cs + lcn)*PIN*PIN + (size_t)h0*PIN + w0;
        #pragma unroll
        for(int r=0;r<XR;r++)
          #pragma unroll
          for(int c=0;c<XC;c++) nv[r][c] = xc[(size_t)r*PIN + c];
      }
      const float4* w4 = (const float4*)(wl + lc*9*CO);
      #pragma unroll
      for(int dh=0;dh<3;dh++){
        float4 wa[NH4], wb[NH4], wc[NH4];
        #pragma unroll
        for(int g=0;g<NH4;g++){
          wa[g] = w4[(dh*3+0)*NH4+g];
          wb[g] = w4[(dh*3+1)*NH4+g];
          wc[g] = w4[(dh*3+2)*NH4+g];
        }
        #pragma unroll
        for(int g=0;g<NH4;g++){
          const float* A  = (const float*)&wa[g];
          const float* Bp = (const float*)&wb[g];
          const float* Cp = (const float*)&wc[g];
          #pragma unroll
          for(int cc=0;cc<4;cc++){
            float wA=A[cc], wB=Bp[cc], wC=Cp[cc];
            #pragma unroll
            for(int px=0;px<PX;px++)
              #pragma unroll
              for(int wx=0;wx<WX;wx++)
                accs[px][wx][g*4+cc] += wA*xv[px+dh][wx] + wB*xv[px+dh][wx+1] + wC*xv[px+dh][wx+2];
          }
        }
      }
      #pragma unroll
      for(int r=0;r<XR;r++)
        #pragma unroll
        for(int c=0;c<XC;c++) xv[r][c] = nv[r][c];
    }
  }

  int co0 = cog*CO;
  #pragma unroll
  for(int co=0; co<CO; co++){
    float bsv = bias[co0+co];
    if constexpr(!POOL){
      const int OS = HW + 2*OPAD;
      size_t plane = (size_t)(b*Cout + co0+co)*OS*OS;
      #pragma unroll
      for(int px=0; px<PX; px++)
        #pragma unroll
        for(int wx=0; wx<WX; wx++){
          size_t idx = plane + (size_t)(h0+px+OPAD)*OS + w0+wx + OPAD;
          float mem = dm[idx] + accs[px][wx][co] + bsv;
          out[idx] = mem > 0.f ? mem : 0.f;
          dm[idx]  = (mem > 0.5f) ? 0.f : 0.3f*mem;
        }
    } else if constexpr(WX==2){
      // thread-local 2x2 pool: rows (2pr,2pr+1) x cols (w0,w0+1)
      size_t dplane = (size_t)(b*Cout + co0+co)*HW*HW;
      const int PS = HW/2 + 2*PPAD;
      size_t pplane = (size_t)(b*Cout + co0+co)*PS*PS;
      #pragma unroll
      for(int pr=0; pr<PX/2; pr++){
        float s = 0.f;
        #pragma unroll
        for(int j=0;j<2;j++)
          #pragma unroll
          for(int wx=0;wx<2;wx++){
            int px = 2*pr+j;
            size_t idx = dplane + (size_t)(h0+px)*HW + w0+wx;
            float mem = dm[idx] + accs[px][wx][co] + bsv;
            float o = mem > 0.f ? mem : 0.f;
            dm[idx] = (mem > 0.5f) ? 0.f : 0.3f*mem;
            s += o;
          }
        size_t pidx = pplane + (size_t)((h0>>1)+pr+PPAD)*PS + tc + PPAD;
        float pm = dmp[pidx] + s*0.25f;
        outp[pidx] = pm > 0.f ? pm : 0.f;
        dmp[pidx]  = (pm > 0.5f) ? 0.f : 0.3f*pm;
      }
    } else {
      // WX=1 pool via lane shuffle (adjacent w)
      size_t dplane = (size_t)(b*Cout + co0+co)*HW*HW;
      float vs[PX/2];
      #pragma unroll
      for(int pr=0;pr<PX/2;pr++) vs[pr]=0.f;
      #pragma unroll
      for(int px=0; px<PX; px++){
        size_t idx = dplane + (size_t)(h0+px)*HW + w0;
        float mem = dm[idx] + accs[px][0][co] + bsv;
        float o = mem > 0.f ? mem : 0.f;
        dm[idx] = (mem > 0.5f) ? 0.f : 0.3f*mem;
        vs[px>>1] += o;
      }
      const int PS = HW/2 + 2*PPAD;
      size_t pplane = (size_t)(b*Cout + co0+co)*PS*PS;
      #pragma unroll
      for(int pr=0; pr<PX/2; pr++){
        float s = vs[pr];
        s += __shfl_xor(s, 1, 64);
        if((w0&1)==0){
          size_t pidx = pplane + (size_t)((h0>>1)+pr+PPAD)*PS + (w0>>1) + PPAD;
          float pm = dmp[pidx] + s*0.25f;
          outp[pidx] = pm > 0.f ? pm : 0.f;
          dmp[pidx]  = (pm > 0.5f) ? 0.f : 0.3f*pm;
        }
      }
    }
  }
}

// ---------------- FC1 partial GEMM -> 32 slices ----------------
__global__ void __launch_bounds__(256)
k_fc1(const float* __restrict__ X, const float* __restrict__ Wf,
      float* __restrict__ u1s){
  __shared__ __align__(16) float lds[4896];
  float* Wl = lds;
  float* Xl = lds + 32*68;
  const int tid = threadIdx.x;
  int ot = blockIdx.x & 7, ks = blockIdx.x >> 3;
  int o0 = ot*32, k0 = ks*256;
  int w_id = tid >> 6, lane = tid & 63;
  int o_l = lane & 7, bg = lane >> 3;
  float acc[4][5];
  #pragma unroll
  for(int i=0;i<4;i++)
    #pragma unroll
    for(int j=0;j<5;j++) acc[i][j]=0.f;

  for(int c=0; c<4; c++){
    int kb = k0 + c*64;
    __syncthreads();
    for(int idx=tid; idx<512; idx+=256){
      int r = idx >> 4, j = idx & 15;
      *(float4*)&Wl[r*68 + j*4] = *(const float4*)&Wf[(size_t)(o0+r)*8192 + kb + j*4];
    }
    for(int idx=tid; idx<640; idx+=256){
      int r = idx >> 4, j = idx & 15;
      float4 v = make_float4(0.f,0.f,0.f,0.f);
      if(r < NB) v = *(const float4*)&X[(size_t)r*8192 + kb + j*4];
      *(float4*)&Xl[r*68 + j*4] = v;
    }
    __syncthreads();
    #pragma unroll
    for(int c4=0; c4<4; c4++){
      int g = w_id*4 + c4;
      float4 wv[4], xv[5];
      #pragma unroll
      for(int oi=0;oi<4;oi++) wv[oi] = *(const float4*)&Wl[(o_l+8*oi)*68 + g*4];
      #pragma unroll
      for(int bi=0;bi<5;bi++) xv[bi] = *(const float4*)&Xl[(bg*5+bi)*68 + g*4];
      #pragma unroll
      for(int oi=0;oi<4;oi++)
        #pragma unroll
        for(int bi=0;bi<5;bi++)
          acc[oi][bi] += wv[oi].x*xv[bi].x + wv[oi].y*xv[bi].y
                       + wv[oi].z*xv[bi].z + wv[oi].w*xv[bi].w;
    }
  }
  __syncthreads();
  if(w_id > 0){
    float* r = lds + ((w_id-1)*64 + lane)*20;
    #pragma unroll
    for(int oi=0;oi<4;oi++)
      #pragma unroll
      for(int bi=0;bi<5;bi++) r[oi*5+bi] = acc[oi][bi];
  }
  __syncthreads();
  if(w_id == 0){
    #pragma unroll
    for(int wv=0;wv<3;wv++){
      float* r = lds + (wv*64 + lane)*20;
      #pragma unroll
      for(int oi=0;oi<4;oi++)
        #pragma unroll
        for(int bi=0;bi<5;bi++) acc[oi][bi] += r[oi*5+bi];
    }
    #pragma unroll
    for(int bi=0;bi<5;bi++){
      int b = bg*5 + bi;
      if(b < NB){
        #pragma unroll
        for(int oi=0;oi<4;oi++)
          u1s[((size_t)ks*NB + b)*256 + o0 + o_l + 8*oi] = acc[oi][bi];
      }
    }
  }
}

// ---------------- FC1-reduce + LIAF + FC2 + LIAF + accumulate ----------------
__global__ void __launch_bounds__(256)
k_fc2(const float* __restrict__ u1s, const float* __restrict__ bf1,
      const float* __restrict__ Wf2, const float* __restrict__ bf2,
      float* __restrict__ dmh1, float* __restrict__ dmh2, float* __restrict__ acc){
  __shared__ float xs[256];
  int b = blockIdx.x;
  int o = threadIdx.x;
  float u = bf1[o];
  const float* p = u1s + (size_t)b*256 + o;
  #pragma unroll
  for(int s=0;s<32;s++) u += p[(size_t)s*NB*256];
  int idx = b*256 + o;
  float mem = dmh1[idx] + u;
  float xo = mem > 0.f ? mem : 0.f;
  dmh1[idx] = (mem > 0.5f) ? 0.f : 0.3f*mem;
  xs[o] = xo;
  __syncthreads();
  int w_id = o >> 6, lane = o & 63;
  for(int oo=w_id; oo<11; oo+=4){
    const float* wr = Wf2 + oo*256;
    float s = xs[lane]*wr[lane] + xs[lane+64]*wr[lane+64]
            + xs[lane+128]*wr[lane+128] + xs[lane+192]*wr[lane+192];
    #pragma unroll
    for(int off=32; off>0; off>>=1) s += __shfl_down(s, off, 64);
    if(lane==0){
      int i2 = b*11 + oo;
      float m2 = dmh2[i2] + s + bf2[oo];
      float ov = m2 > 0.f ? m2 : 0.f;
      dmh2[i2] = (m2 > 0.5f) ? 0.f : 0.3f*m2;
      acc[i2] += ov * (1.0f/60.0f);
    }
  }
}

// ==================== launch (single stream, serial) ====================
extern "C" void kernel_launch(void* const* d_in, const int* in_sizes, int n_in,
                              void* d_out, int out_size, void* d_ws, size_t ws_size,
                              hipStream_t stream) {
  Params p;
  p.data = (const float*)d_in[0];
  p.W0  = (const float*)d_in[2];  p.b0  = (const float*)d_in[3];
  p.W1  = (const float*)d_in[4];  p.b1  = (const float*)d_in[5];
  p.W2  = (const float*)d_in[6];  p.b2  = (const float*)d_in[7];
  p.Wf1 = (const float*)d_in[8];  p.bf1 = (const float*)d_in[9];
  p.Wf2 = (const float*)d_in[10]; p.bf2 = (const float*)d_in[11];
  p.acc = (float*)d_out;

  float* ws = (float*)d_ws;
  const size_t S_XB    = (size_t)NT*NB*2*34*34;
  const size_t S_W0T   = 2*9*64;
  const size_t S_W1T   = 64*9*128;
  const size_t S_W2T   = 128*9*128;
  const size_t S_OUT0  = (size_t)NB*64*34*34;
  const size_t S_OP1   = (size_t)NB*128*18*18;
  const size_t S_OP2   = (size_t)NB*128*8*8;
  const size_t S_U1S   = (size_t)32*NB*256;
  const size_t S_DM0   = S_OUT0;
  const size_t S_DM1   = (size_t)NB*128*32*32;
  const size_t S_DMP1  = S_OP1;
  const size_t S_DM2   = (size_t)NB*128*16*16;
  const size_t S_DMP2  = S_OP2;
  const size_t S_OH1   = (size_t)NB*256;

  p.xb    = ws;  ws += S_XB;
  p.w0t   = ws;  ws += S_W0T;
  p.w1t   = ws;  ws += S_W1T;
  p.w2t   = ws;  ws += S_W2T;
  p.zbase = ws;
  p.out0  = ws;  ws += S_OUT0;
  p.outp1 = ws;  ws += S_OP1;
  p.outp2 = ws;  ws += S_OP2;
  p.u1s   = ws;  ws += S_U1S;
  p.dm0   = ws;  ws += S_DM0;
  p.dm1   = ws;  ws += S_DM1;
  p.dmp1  = ws;  ws += S_DMP1;
  p.dm2   = ws;  ws += S_DM2;
  p.dmp2  = ws;  ws += S_DMP2;
  p.dmh1  = ws;  ws += S_OH1;
  p.dmh2  = ws;  ws += (size_t)NB*11;
  p.zn4   = (int)((ws - p.zbase) / 4);

  k_prep<<<dim3(1024), dim3(256), 0, stream>>>(p);
  for(int t=0; t<NT; t++){
    const float* xt = p.xb + (size_t)t*NB*2*34*34;
    // conv0: 2->64 @32x32, PX=4, WX=1, 256thr, out padded (288 blocks)
    k_conv<2,64,32,8,4,1,8,0,1,0,2><<<dim3(288), dim3(256), 0, stream>>>(
        xt, p.w0t, p.b0, p.dm0, p.out0, nullptr, nullptr);
    // conv1+pool1: 64->128 @32x32, PX=8, WX=1, TY=4, 128thr (576 blocks)
    k_conv<64,128,32,8,8,1,4,1,0,1,64><<<dim3(576), dim3(128), 0, stream>>>(
        p.out0, p.w1t, p.b1, p.dm1, nullptr, p.dmp1, p.outp1);
    // conv2+pool2: 128->128 @16x16, PX=2, WX=2, TY=8, 64thr, CS=32 (576 blocks)
    k_conv<128,128,16,8,2,2,8,1,0,0,32><<<dim3(576), dim3(64), 0, stream>>>(
        p.outp1, p.w2t, p.b2, p.dm2, nullptr, p.dmp2, p.outp2);
    // fc1 -> 32 slices (256 blocks)
    k_fc1<<<dim3(256), dim3(256), 0, stream>>>(p.outp2, p.Wf1, p.u1s);
    // fc1-reduce + LIAF + fc2 + LIAF + accumulate (36 blocks)
    k_fc2<<<dim3(36), dim3(256), 0, stream>>>(p.u1s, p.bf1, p.Wf2, p.bf2,
                                              p.dmh1, p.dmh2, p.acc);
  }
}

// Round 11
// 13228.320 us; speedup vs baseline: 1.4025x; 1.4025x over previous
//
#include <hip/hip_runtime.h>

#define NB 36
#define NT 60

struct Params {
  const float *data;
  const float *W0, *b0, *W1, *b1, *W2, *b2, *Wf1, *bf1, *Wf2, *bf2;
  float *xb, *w0t, *w1t, *w2t;
  float *out0, *outp1, *outp2, *u1s;
  float *dm0, *dm1, *dmp1, *dm2, *dmp2, *dmh1, *dmh2;
  float *acc;
  float *zbase; int zn4;
};

__global__ void __launch_bounds__(256) k_prep(Params p){
  int gt  = blockIdx.x*256 + threadIdx.x;
  int STR = gridDim.x*256;
  if(gt < NB*11) p.acc[gt] = 0.f;
  for(int i=gt; i<p.zn4; i+=STR) ((float4*)p.zbase)[i] = make_float4(0.f,0.f,0.f,0.f);
  const int PLANE = 34*34;
  for(int i=gt; i<NT*NB*2*PLANE; i+=STR){
    int t   = i / (NB*2*PLANE);
    int rem = i % (NB*2*PLANE);
    int bc  = rem / PLANE;
    int pix = rem % PLANE;
    int ph = pix/34, pw = pix%34;
    float v = 0.f;
    if(ph>=1 && ph<=32 && pw>=1 && pw<=32){
      float d = p.data[((size_t)bc*1024 + (ph-1)*32 + (pw-1))*NT + t];
      v = (d > 1.0f) ? 1.0f : 0.0f;
    }
    p.xb[i] = v;
  }
  for(int i=gt; i<2*9*64; i+=STR){
    int co=i%64, rr=i/64; p.w0t[i] = p.W0[(co*2 + rr/9)*9 + rr%9];
  }
  for(int i=gt; i<64*9*128; i+=STR){
    int co=i%128, rr=i/128; p.w1t[i] = p.W1[(co*64 + rr/9)*9 + rr%9];
  }
  for(int i=gt; i<128*9*128; i+=STR){
    int co=i%128, rr=i/128; p.w2t[i] = p.W2[(co*128 + rr/9)*9 + rr%9];
  }
}

// ---------------- fused conv3x3 + LIAF (+ optional avgpool2 + LIAF) ----------------
// Halo-padded input (stride HW+2) -> no bounds checks. Weights in LDS, float4
// broadcast reads. Thread: tc=tid%(HW/WX) covers WX columns, PX rows, CO couts.
// Register-double-buffered input prefetch across cin.
// WX=2 && POOL: 2x2 pool patch thread-local (no shuffles/predication).
template<int Cin,int Cout,int HW,int CO,int PX,int WX,int TY,int POOL,int OPAD,int PPAD,int CS>
__global__ void __launch_bounds__((HW/WX)*TY)
k_conv(const float* __restrict__ x, const float* __restrict__ wt,
       const float* __restrict__ bias, float* __restrict__ dm,
       float* __restrict__ out, float* __restrict__ dmp, float* __restrict__ outp)
{
  const int NCOG = Cout/CO;
  const int TH   = PX*TY;
  const int NHG  = HW/TH;
  const int NH4  = CO/4;
  const int NTHL = (HW/WX)*TY;
  const int PIN  = HW+2;
  const int XR   = PX+2, XC = WX+2;
  int tile = blockIdx.x;
  int tid  = threadIdx.x;
  int cog = tile % NCOG;
  int hg  = (tile/NCOG) % NHG;
  int b   = tile/(NCOG*NHG);
  int tc  = tid % (HW/WX);
  int ty  = tid / (HW/WX);
  int w0  = tc*WX;
  int h0  = hg*TH + ty*PX;

  __shared__ __align__(16) float wl[CS*9*CO];

  float accs[PX][WX][CO];
  #pragma unroll
  for(int p=0;p<PX;p++)
    #pragma unroll
    for(int q=0;q<WX;q++)
      #pragma unroll
      for(int c=0;c<CO;c++) accs[p][q][c]=0.f;

  for(int cs=0; cs<Cin; cs+=CS){
    __syncthreads();
    for(int j=tid; j<CS*9*CO; j+=NTHL){
      int c  = j % CO;
      int rr = j / CO;
      wl[j] = wt[(cs*9 + rr)*Cout + cog*CO + c];
    }
    __syncthreads();

    float xv[XR][XC];
    {
      const float* xc = x + ((size_t)b*Cin + cs)*PIN*PIN + (size_t)h0*PIN + w0;
      #pragma unroll
      for(int r=0;r<XR;r++)
        #pragma unroll
        for(int c=0;c<XC;c++) xv[r][c] = xc[(size_t)r*PIN + c];
    }

    for(int lc=0; lc<CS; lc++){
      int lcn = (lc+1 < CS) ? lc+1 : lc;
      float nv[XR][XC];
      {
        const float* xc = x + ((size_t)b*Cin + cs + lcn)*PIN*PIN + (size_t)h0*PIN + w0;
        #pragma unroll
        for(int r=0;r<XR;r++)
          #pragma unroll
          for(int c=0;c<XC;c++) nv[r][c] = xc[(size_t)r*PIN + c];
      }
      const float4* w4 = (const float4*)(wl + lc*9*CO);
      #pragma unroll
      for(int dh=0;dh<3;dh++){
        float4 wa[NH4], wb[NH4], wc[NH4];
        #pragma unroll
        for(int g=0;g<NH4;g++){
          wa[g] = w4[(dh*3+0)*NH4+g];
          wb[g] = w4[(dh*3+1)*NH4+g];
          wc[g] = w4[(dh*3+2)*NH4+g];
        }
        #pragma unroll
        for(int g=0;g<NH4;g++){
          const float* A  = (const float*)&wa[g];
          const float* Bp = (const float*)&wb[g];
          const float* Cp = (const float*)&wc[g];
          #pragma unroll
          for(int cc=0;cc<4;cc++){
            float wA=A[cc], wB=Bp[cc], wC=Cp[cc];
            #pragma unroll
            for(int px=0;px<PX;px++)
              #pragma unroll
              for(int wx=0;wx<WX;wx++)
                accs[px][wx][g*4+cc] += wA*xv[px+dh][wx] + wB*xv[px+dh][wx+1] + wC*xv[px+dh][wx+2];
          }
        }
      }
      #pragma unroll
      for(int r=0;r<XR;r++)
        #pragma unroll
        for(int c=0;c<XC;c++) xv[r][c] = nv[r][c];
    }
  }

  int co0 = cog*CO;
  #pragma unroll
  for(int co=0; co<CO; co++){
    float bsv = bias[co0+co];
    if constexpr(!POOL){
      const int OS = HW + 2*OPAD;
      size_t plane = (size_t)(b*Cout + co0+co)*OS*OS;
      #pragma unroll
      for(int px=0; px<PX; px++)
        #pragma unroll
        for(int wx=0; wx<WX; wx++){
          size_t idx = plane + (size_t)(h0+px+OPAD)*OS + w0+wx + OPAD;
          float mem = dm[idx] + accs[px][wx][co] + bsv;
          out[idx] = mem > 0.f ? mem : 0.f;
          dm[idx]  = (mem > 0.5f) ? 0.f : 0.3f*mem;
        }
    } else if constexpr(WX==2){
      // thread-local 2x2 pool: rows (2pr,2pr+1) x cols (w0,w0+1)
      size_t dplane = (size_t)(b*Cout + co0+co)*HW*HW;
      const int PS = HW/2 + 2*PPAD;
      size_t pplane = (size_t)(b*Cout + co0+co)*PS*PS;
      #pragma unroll
      for(int pr=0; pr<PX/2; pr++){
        float s = 0.f;
        #pragma unroll
        for(int j=0;j<2;j++)
          #pragma unroll
          for(int wx=0;wx<2;wx++){
            int px = 2*pr+j;
            size_t idx = dplane + (size_t)(h0+px)*HW + w0+wx;
            float mem = dm[idx] + accs[px][wx][co] + bsv;
            float o = mem > 0.f ? mem : 0.f;
            dm[idx] = (mem > 0.5f) ? 0.f : 0.3f*mem;
            s += o;
          }
        size_t pidx = pplane + (size_t)((h0>>1)+pr+PPAD)*PS + tc + PPAD;
        float pm = dmp[pidx] + s*0.25f;
        outp[pidx] = pm > 0.f ? pm : 0.f;
        dmp[pidx]  = (pm > 0.5f) ? 0.f : 0.3f*pm;
      }
    } else {
      // WX=1 pool via lane shuffle (adjacent w)
      size_t dplane = (size_t)(b*Cout + co0+co)*HW*HW;
      float vs[PX/2];
      #pragma unroll
      for(int pr=0;pr<PX/2;pr++) vs[pr]=0.f;
      #pragma unroll
      for(int px=0; px<PX; px++){
        size_t idx = dplane + (size_t)(h0+px)*HW + w0;
        float mem = dm[idx] + accs[px][0][co] + bsv;
        float o = mem > 0.f ? mem : 0.f;
        dm[idx] = (mem > 0.5f) ? 0.f : 0.3f*mem;
        vs[px>>1] += o;
      }
      const int PS = HW/2 + 2*PPAD;
      size_t pplane = (size_t)(b*Cout + co0+co)*PS*PS;
      #pragma unroll
      for(int pr=0; pr<PX/2; pr++){
        float s = vs[pr];
        s += __shfl_xor(s, 1, 64);
        if((w0&1)==0){
          size_t pidx = pplane + (size_t)((h0>>1)+pr+PPAD)*PS + (w0>>1) + PPAD;
          float pm = dmp[pidx] + s*0.25f;
          outp[pidx] = pm > 0.f ? pm : 0.f;
          dmp[pidx]  = (pm > 0.5f) ? 0.f : 0.3f*pm;
        }
      }
    }
  }
}

// ---------------- FC1 partial GEMM -> 32 slices ----------------
__global__ void __launch_bounds__(256)
k_fc1(const float* __restrict__ X, const float* __restrict__ Wf,
      float* __restrict__ u1s){
  __shared__ __align__(16) float lds[4896];
  float* Wl = lds;
  float* Xl = lds + 32*68;
  const int tid = threadIdx.x;
  int ot = blockIdx.x & 7, ks = blockIdx.x >> 3;
  int o0 = ot*32, k0 = ks*256;
  int w_id = tid >> 6, lane = tid & 63;
  int o_l = lane & 7, bg = lane >> 3;
  float acc[4][5];
  #pragma unroll
  for(int i=0;i<4;i++)
    #pragma unroll
    for(int j=0;j<5;j++) acc[i][j]=0.f;

  for(int c=0; c<4; c++){
    int kb = k0 + c*64;
    __syncthreads();
    for(int idx=tid; idx<512; idx+=256){
      int r = idx >> 4, j = idx & 15;
      *(float4*)&Wl[r*68 + j*4] = *(const float4*)&Wf[(size_t)(o0+r)*8192 + kb + j*4];
    }
    for(int idx=tid; idx<640; idx+=256){
      int r = idx >> 4, j = idx & 15;
      float4 v = make_float4(0.f,0.f,0.f,0.f);
      if(r < NB) v = *(const float4*)&X[(size_t)r*8192 + kb + j*4];
      *(float4*)&Xl[r*68 + j*4] = v;
    }
    __syncthreads();
    #pragma unroll
    for(int c4=0; c4<4; c4++){
      int g = w_id*4 + c4;
      float4 wv[4], xv[5];
      #pragma unroll
      for(int oi=0;oi<4;oi++) wv[oi] = *(const float4*)&Wl[(o_l+8*oi)*68 + g*4];
      #pragma unroll
      for(int bi=0;bi<5;bi++) xv[bi] = *(const float4*)&Xl[(bg*5+bi)*68 + g*4];
      #pragma unroll
      for(int oi=0;oi<4;oi++)
        #pragma unroll
        for(int bi=0;bi<5;bi++)
          acc[oi][bi] += wv[oi].x*xv[bi].x + wv[oi].y*xv[bi].y
                       + wv[oi].z*xv[bi].z + wv[oi].w*xv[bi].w;
    }
  }
  __syncthreads();
  if(w_id > 0){
    float* r = lds + ((w_id-1)*64 + lane)*20;
    #pragma unroll
    for(int oi=0;oi<4;oi++)
      #pragma unroll
      for(int bi=0;bi<5;bi++) r[oi*5+bi] = acc[oi][bi];
  }
  __syncthreads();
  if(w_id == 0){
    #pragma unroll
    for(int wv=0;wv<3;wv++){
      float* r = lds + (wv*64 + lane)*20;
      #pragma unroll
      for(int oi=0;oi<4;oi++)
        #pragma unroll
        for(int bi=0;bi<5;bi++) acc[oi][bi] += r[oi*5+bi];
    }
    #pragma unroll
    for(int bi=0;bi<5;bi++){
      int b = bg*5 + bi;
      if(b < NB){
        #pragma unroll
        for(int oi=0;oi<4;oi++)
          u1s[((size_t)ks*NB + b)*256 + o0 + o_l + 8*oi] = acc[oi][bi];
      }
    }
  }
}

// ---------------- FC1-reduce + LIAF + FC2 + LIAF + accumulate ----------------
__global__ void __launch_bounds__(256)
k_fc2(const float* __restrict__ u1s, const float* __restrict__ bf1,
      const float* __restrict__ Wf2, const float* __restrict__ bf2,
      float* __restrict__ dmh1, float* __restrict__ dmh2, float* __restrict__ acc){
  __shared__ float xs[256];
  int b = blockIdx.x;
  int o = threadIdx.x;
  float u = bf1[o];
  const float* p = u1s + (size_t)b*256 + o;
  #pragma unroll
  for(int s=0;s<32;s++) u += p[(size_t)s*NB*256];
  int idx = b*256 + o;
  float mem = dmh1[idx] + u;
  float xo = mem > 0.f ? mem : 0.f;
  dmh1[idx] = (mem > 0.5f) ? 0.f : 0.3f*mem;
  xs[o] = xo;
  __syncthreads();
  int w_id = o >> 6, lane = o & 63;
  for(int oo=w_id; oo<11; oo+=4){
    const float* wr = Wf2 + oo*256;
    float s = xs[lane]*wr[lane] + xs[lane+64]*wr[lane+64]
            + xs[lane+128]*wr[lane+128] + xs[lane+192]*wr[lane+192];
    #pragma unroll
    for(int off=32; off>0; off>>=1) s += __shfl_down(s, off, 64);
    if(lane==0){
      int i2 = b*11 + oo;
      float m2 = dmh2[i2] + s + bf2[oo];
      float ov = m2 > 0.f ? m2 : 0.f;
      dmh2[i2] = (m2 > 0.5f) ? 0.f : 0.3f*m2;
      acc[i2] += ov * (1.0f/60.0f);
    }
  }
}

// ==================== launch (single stream, serial) ====================
extern "C" void kernel_launch(void* const* d_in, const int* in_sizes, int n_in,
                              void* d_out, int out_size, void* d_ws, size_t ws_size,
                              hipStream_t stream) {
  Params p;
  p.data = (const float*)d_in[0];
  p.W0  = (const float*)d_in[2];  p.b0  = (const float*)d_in[3];
  p.W1  = (const float*)d_in[4];  p.b1  = (const float*)d_in[5];
  p.W2  = (const float*)d_in[6];  p.b2  = (const float*)d_in[7];
  p.Wf1 = (const float*)d_in[8];  p.bf1 = (const float*)d_in[9];
  p.Wf2 = (const float*)d_in[10]; p.bf2 = (const float*)d_in[11];
  p.acc = (float*)d_out;

  float* ws = (float*)d_ws;
  const size_t S_XB    = (size_t)NT*NB*2*34*34;
  const size_t S_W0T   = 2*9*64;
  const size_t S_W1T   = 64*9*128;
  const size_t S_W2T   = 128*9*128;
  const size_t S_OUT0  = (size_t)NB*64*34*34;
  const size_t S_OP1   = (size_t)NB*128*18*18;
  const size_t S_OP2   = (size_t)NB*128*8*8;
  const size_t S_U1S   = (size_t)32*NB*256;
  const size_t S_DM0   = S_OUT0;
  const size_t S_DM1   = (size_t)NB*128*32*32;
  const size_t S_DMP1  = S_OP1;
  const size_t S_DM2   = (size_t)NB*128*16*16;
  const size_t S_DMP2  = S_OP2;
  const size_t S_OH1   = (size_t)NB*256;

  p.xb    = ws;  ws += S_XB;
  p.w0t   = ws;  ws += S_W0T;
  p.w1t   = ws;  ws += S_W1T;
  p.w2t   = ws;  ws += S_W2T;
  p.zbase = ws;
  p.out0  = ws;  ws += S_OUT0;
  p.outp1 = ws;  ws += S_OP1;
  p.outp2 = ws;  ws += S_OP2;
  p.u1s   = ws;  ws += S_U1S;
  p.dm0   = ws;  ws += S_DM0;
  p.dm1   = ws;  ws += S_DM1;
  p.dmp1  = ws;  ws += S_DMP1;
  p.dm2   = ws;  ws += S_DM2;
  p.dmp2  = ws;  ws += S_DMP2;
  p.dmh1  = ws;  ws += S_OH1;
  p.dmh2  = ws;  ws += (size_t)NB*11;
  p.zn4   = (int)((ws - p.zbase) / 4);

  k_prep<<<dim3(1024), dim3(256), 0, stream>>>(p);
  for(int t=0; t<NT; t++){
    const float* xt = p.xb + (size_t)t*NB*2*34*34;
    // conv0: 2->64 @32x32, CO=8, PX=4, WX=1, TY=8, 256thr, out padded (288 blocks)
    k_conv<2,64,32,8,4,1,8,0,1,0,2><<<dim3(288), dim3(256), 0, stream>>>(
        xt, p.w0t, p.b0, p.dm0, p.out0, nullptr, nullptr);
    // conv1+pool1: 64->128 @32x32, CO=4, PX=4, WX=2, TY=8, 128thr (1152 blocks)
    //   accs=32 regs (same as R9-best), LDS weight bytes/FMA halved
    k_conv<64,128,32,4,4,2,8,1,0,1,64><<<dim3(36*32), dim3(128), 0, stream>>>(
        p.out0, p.w1t, p.b1, p.dm1, nullptr, p.dmp1, p.outp1);
    // conv2+pool2: 128->128 @16x16, CO=4, PX=2, WX=1, TY=4, 64thr (2304 blocks) — R9 exact
    k_conv<128,128,16,4,2,1,4,1,0,0,64><<<dim3(2304), dim3(64), 0, stream>>>(
        p.outp1, p.w2t, p.b2, p.dm2, nullptr, p.dmp2, p.outp2);
    // fc1 -> 32 slices (256 blocks)
    k_fc1<<<dim3(256), dim3(256), 0, stream>>>(p.outp2, p.Wf1, p.u1s);
    // fc1-reduce + LIAF + fc2 + LIAF + accumulate (36 blocks)
    k_fc2<<<dim3(36), dim3(256), 0, stream>>>(p.u1s, p.bf1, p.Wf2, p.bf2,
                                              p.dmh1, p.dmh2, p.acc);
  }
}

// Round 13
// 11152.145 us; speedup vs baseline: 1.6636x; 1.1862x over previous
//
#include <hip/hip_runtime.h>

#define NB 36
#define NT 60

typedef __attribute__((ext_vector_type(8))) short short8;
typedef __attribute__((ext_vector_type(4))) float f32x4;

struct Params {
  const float *data;
  const float *W0, *b0, *W1, *b1, *W2, *b2, *Wf1, *bf1, *Wf2, *bf2;
  float *xb, *w0t, *w2t;
  unsigned short *w1h, *w1l, *xh, *xl;
  float *outp1, *outp2, *u1s;
  float *dm0, *dm1, *dmp1, *dm2, *dmp2, *dmh1, *dmh2;
  float *acc;
  float *zbase; int zn4;
};

// round-to-nearest-even bf16 (truncation here was R12's failure: one-sided
// residual -> bias accumulates linearly over K=576)
__device__ __forceinline__ unsigned short bf16_rne(float v){
  unsigned int bits = __float_as_uint(v);
  unsigned int r = bits + 0x7FFFu + ((bits >> 16) & 1u);
  return (unsigned short)(r >> 16);
}
__device__ __forceinline__ void bf16split(float v, unsigned short& h, unsigned short& l){
  h = bf16_rne(v);
  float hf = __uint_as_float((unsigned int)h << 16);
  l = bf16_rne(v - hf);
}

// ---------------- prep ----------------
__global__ void __launch_bounds__(256) k_prep(Params p){
  int gt  = blockIdx.x*256 + threadIdx.x;
  int STR = gridDim.x*256;
  if(gt < NB*11) p.acc[gt] = 0.f;
  for(int i=gt; i<p.zn4; i+=STR) ((float4*)p.zbase)[i] = make_float4(0.f,0.f,0.f,0.f);
  const int PLANE = 34*34;
  for(int i=gt; i<NT*NB*2*PLANE; i+=STR){
    int t   = i / (NB*2*PLANE);
    int rem = i % (NB*2*PLANE);
    int bc  = rem / PLANE;
    int pix = rem % PLANE;
    int ph = pix/34, pw = pix%34;
    float v = 0.f;
    if(ph>=1 && ph<=32 && pw>=1 && pw<=32){
      float d = p.data[((size_t)bc*1024 + (ph-1)*32 + (pw-1))*NT + t];
      v = (d > 1.0f) ? 1.0f : 0.0f;
    }
    p.xb[i] = v;
  }
  for(int i=gt; i<2*9*64; i+=STR){
    int co=i%64, rr=i/64; p.w0t[i] = p.W0[(co*2 + rr/9)*9 + rr%9];
  }
  // w1 split to bf16 hi/lo (RNE), layout [cout][k=cin*9+dd]
  for(int i=gt; i<128*576; i+=STR){
    int co = i/576, k = i%576;
    int cin = k/9, dd = k%9;
    float v = p.W1[(co*64+cin)*9 + dd];
    unsigned short h,l; bf16split(v,h,l);
    p.w1h[i]=h; p.w1l[i]=l;
  }
  for(int i=gt; i<128*9*128; i+=STR){
    int co=i%128, rr=i/128; p.w2t[i] = p.W2[(co*128 + rr/9)*9 + rr%9];
  }
}

// ---------------- fused conv3x3 + LIAF (+pool) — fp32 path (conv0, conv2) ----------------
template<int Cin,int Cout,int HW,int CO,int PX,int WX,int TY,int POOL,int OPAD,int PPAD,int CS,int BF16O>
__global__ void __launch_bounds__((HW/WX)*TY)
k_conv(const float* __restrict__ x, const float* __restrict__ wt,
       const float* __restrict__ bias, float* __restrict__ dm,
       float* __restrict__ out, float* __restrict__ dmp, float* __restrict__ outp,
       unsigned short* __restrict__ outh, unsigned short* __restrict__ outl)
{
  const int NCOG = Cout/CO;
  const int TH   = PX*TY;
  const int NHG  = HW/TH;
  const int NH4  = CO/4;
  const int NTHL = (HW/WX)*TY;
  const int PIN  = HW+2;
  const int XR   = PX+2, XC = WX+2;
  int tile = blockIdx.x;
  int tid  = threadIdx.x;
  int cog = tile % NCOG;
  int hg  = (tile/NCOG) % NHG;
  int b   = tile/(NCOG*NHG);
  int tc  = tid % (HW/WX);
  int ty  = tid / (HW/WX);
  int w0  = tc*WX;
  int h0  = hg*TH + ty*PX;

  __shared__ __align__(16) float wl[CS*9*CO];

  float accs[PX][WX][CO];
  #pragma unroll
  for(int p=0;p<PX;p++)
    #pragma unroll
    for(int q=0;q<WX;q++)
      #pragma unroll
      for(int c=0;c<CO;c++) accs[p][q][c]=0.f;

  for(int cs=0; cs<Cin; cs+=CS){
    __syncthreads();
    for(int j=tid; j<CS*9*CO; j+=NTHL){
      int c  = j % CO;
      int rr = j / CO;
      wl[j] = wt[(cs*9 + rr)*Cout + cog*CO + c];
    }
    __syncthreads();

    float xv[XR][XC];
    {
      const float* xc = x + ((size_t)b*Cin + cs)*PIN*PIN + (size_t)h0*PIN + w0;
      #pragma unroll
      for(int r=0;r<XR;r++)
        #pragma unroll
        for(int c=0;c<XC;c++) xv[r][c] = xc[(size_t)r*PIN + c];
    }

    for(int lc=0; lc<CS; lc++){
      int lcn = (lc+1 < CS) ? lc+1 : lc;
      float nv[XR][XC];
      {
        const float* xc = x + ((size_t)b*Cin + cs + lcn)*PIN*PIN + (size_t)h0*PIN + w0;
        #pragma unroll
        for(int r=0;r<XR;r++)
          #pragma unroll
          for(int c=0;c<XC;c++) nv[r][c] = xc[(size_t)r*PIN + c];
      }
      const float4* w4 = (const float4*)(wl + lc*9*CO);
      #pragma unroll
      for(int dh=0;dh<3;dh++){
        float4 wa[NH4], wb[NH4], wc[NH4];
        #pragma unroll
        for(int g=0;g<NH4;g++){
          wa[g] = w4[(dh*3+0)*NH4+g];
          wb[g] = w4[(dh*3+1)*NH4+g];
          wc[g] = w4[(dh*3+2)*NH4+g];
        }
        #pragma unroll
        for(int g=0;g<NH4;g++){
          const float* A  = (const float*)&wa[g];
          const float* Bp = (const float*)&wb[g];
          const float* Cp = (const float*)&wc[g];
          #pragma unroll
          for(int cc=0;cc<4;cc++){
            float wA=A[cc], wB=Bp[cc], wC=Cp[cc];
            #pragma unroll
            for(int px=0;px<PX;px++)
              #pragma unroll
              for(int wx=0;wx<WX;wx++)
                accs[px][wx][g*4+cc] += wA*xv[px+dh][wx] + wB*xv[px+dh][wx+1] + wC*xv[px+dh][wx+2];
          }
        }
      }
      #pragma unroll
      for(int r=0;r<XR;r++)
        #pragma unroll
        for(int c=0;c<XC;c++) xv[r][c] = nv[r][c];
    }
  }

  int co0 = cog*CO;
  #pragma unroll
  for(int co=0; co<CO; co++){
    float bsv = bias[co0+co];
    if constexpr(!POOL){
      const int OS = HW + 2*OPAD;
      size_t plane = (size_t)(b*Cout + co0+co)*OS*OS;
      #pragma unroll
      for(int px=0; px<PX; px++)
        #pragma unroll
        for(int wx=0; wx<WX; wx++){
          size_t idx = plane + (size_t)(h0+px+OPAD)*OS + w0+wx + OPAD;
          float mem = dm[idx] + accs[px][wx][co] + bsv;
          float ov = mem > 0.f ? mem : 0.f;
          dm[idx]  = (mem > 0.5f) ? 0.f : 0.3f*mem;
          if constexpr(BF16O){
            unsigned short h,l; bf16split(ov,h,l);
            outh[idx]=h; outl[idx]=l;
          } else {
            out[idx] = ov;
          }
        }
    } else {
      size_t dplane = (size_t)(b*Cout + co0+co)*HW*HW;
      float vs[PX/2];
      #pragma unroll
      for(int pr=0;pr<PX/2;pr++) vs[pr]=0.f;
      #pragma unroll
      for(int px=0; px<PX; px++){
        size_t idx = dplane + (size_t)(h0+px)*HW + w0;
        float mem = dm[idx] + accs[px][0][co] + bsv;
        float o = mem > 0.f ? mem : 0.f;
        dm[idx] = (mem > 0.5f) ? 0.f : 0.3f*mem;
        vs[px>>1] += o;
      }
      const int PS = HW/2 + 2*PPAD;
      size_t pplane = (size_t)(b*Cout + co0+co)*PS*PS;
      #pragma unroll
      for(int pr=0; pr<PX/2; pr++){
        float s = vs[pr];
        s += __shfl_xor(s, 1, 64);
        if((w0&1)==0){
          size_t pidx = pplane + (size_t)((h0>>1)+pr+PPAD)*PS + (w0>>1) + PPAD;
          float pm = dmp[pidx] + s*0.25f;
          outp[pidx] = pm > 0.f ? pm : 0.f;
          dmp[pidx]  = (pm > 0.5f) ? 0.f : 0.3f*pm;
        }
      }
    }
  }
}

// ---------------- conv1: implicit-GEMM MFMA bf16x3 + LIAF + pool ----------------
// Grid 576 = 36 b x 2 cog x 8 pxg. Block: 64 cout x 128 px (4 rows x 32 cols).
// K = 576 in 18 chunks of 32. A (w1) staged [co][k] pitch 40; X im2col [px][k].
__global__ void __launch_bounds__(256)
k_conv1(const unsigned short* __restrict__ xh, const unsigned short* __restrict__ xl,
        const unsigned short* __restrict__ w1h, const unsigned short* __restrict__ w1l,
        const float* __restrict__ bias, float* __restrict__ dm,
        float* __restrict__ dmp, float* __restrict__ outp)
{
  __shared__ unsigned short lds[15360];
  unsigned short* Ah = lds;           // 64*40
  unsigned short* Al = lds + 2560;
  unsigned short* Xh = lds + 5120;    // 128*40
  unsigned short* Xl = lds + 10240;

  int bid = blockIdx.x;
  int cog = bid & 1;
  int pxg = (bid>>1) & 7;
  int b   = bid >> 4;
  int tid = threadIdx.x;
  int wv  = tid >> 6, lane = tid & 63;
  int wm = wv & 1, wn = wv >> 1;
  int n = lane & 15, quad = lane >> 4;
  int r0 = pxg*4;

  f32x4 acc[2][4];
  #pragma unroll
  for(int mo=0;mo<2;mo++)
    #pragma unroll
    for(int no=0;no<4;no++) acc[mo][no] = (f32x4){0.f,0.f,0.f,0.f};

  int aco = tid >> 2;
  int aq  = tid & 3;
  const unsigned short* whp = w1h + (size_t)(cog*64 + aco)*576 + aq*8;
  const unsigned short* wlp = w1l + (size_t)(cog*64 + aco)*576 + aq*8;
  int sk  = tid >> 3;
  int pxq = tid & 7;
  int srow = pxq >> 1;
  int scol = (pxq & 1) * 16;
  int pxb  = pxq * 16;

  for(int ch=0; ch<18; ch++){
    int k0 = ch*32;
    __syncthreads();
    *(uint4*)&Ah[aco*40 + aq*8] = *(const uint4*)(whp + k0);
    *(uint4*)&Al[aco*40 + aq*8] = *(const uint4*)(wlp + k0);
    int kg = k0 + sk;
    int cin = kg / 9;
    int dd  = kg - cin*9;
    int dh = dd/3, dw = dd - dh*3;
    size_t soff = ((size_t)(b*64 + cin)*34 + (r0 + srow + dh))*34 + scol + dw;
    const unsigned short* sh = xh + soff;
    const unsigned short* sl = xl + soff;
    #pragma unroll
    for(int i=0;i<16;i++){
      Xh[(pxb+i)*40 + sk] = sh[i];
      Xl[(pxb+i)*40 + sk] = sl[i];
    }
    __syncthreads();

    short8 ahf[2], alf[2];
    #pragma unroll
    for(int mo=0;mo<2;mo++){
      int row = wm*32 + mo*16 + n;
      ahf[mo] = *(const short8*)&Ah[row*40 + quad*8];
      alf[mo] = *(const short8*)&Al[row*40 + quad*8];
    }
    #pragma unroll
    for(int no=0;no<4;no++){
      int prow = wn*64 + no*16 + n;
      short8 xhf = *(const short8*)&Xh[prow*40 + quad*8];
      short8 xlf = *(const short8*)&Xl[prow*40 + quad*8];
      #pragma unroll
      for(int mo=0;mo<2;mo++){
        acc[mo][no] = __builtin_amdgcn_mfma_f32_16x16x32_bf16(ahf[mo], xhf, acc[mo][no],0,0,0);
        acc[mo][no] = __builtin_amdgcn_mfma_f32_16x16x32_bf16(ahf[mo], xlf, acc[mo][no],0,0,0);
        acc[mo][no] = __builtin_amdgcn_mfma_f32_16x16x32_bf16(alf[mo], xhf, acc[mo][no],0,0,0);
      }
    }
  }

  // epilogue: LIAF (dm1 packed 32x32) + 2x2 pool (outp1 padded 18x18)
  #pragma unroll
  for(int mo=0;mo<2;mo++){
    #pragma unroll
    for(int reg=0;reg<4;reg++){
      int co = cog*64 + wm*32 + mo*16 + quad*4 + reg;
      float bsv = bias[co];
      float o[4];
      #pragma unroll
      for(int no=0;no<4;no++){
        int r = r0 + wn*2 + (no>>1);
        int c = (no&1)*16 + n;
        size_t idx = (((size_t)b*128 + co)*32 + r)*32 + c;
        float mem = dm[idx] + acc[mo][no][reg] + bsv;
        o[no] = mem > 0.f ? mem : 0.f;
        dm[idx] = (mem > 0.5f) ? 0.f : 0.3f*mem;
      }
      #pragma unroll
      for(int pp=0; pp<2; pp++){
        float s = o[pp] + o[pp+2];
        s += __shfl_xor(s, 1, 64);
        if((n&1)==0){
          int pr = pxg*2 + wn;
          int pc = pp*8 + (n>>1);
          size_t pidx = (((size_t)b*128 + co)*18 + pr+1)*18 + pc+1;
          float pm = dmp[pidx] + s*0.25f;
          outp[pidx] = pm > 0.f ? pm : 0.f;
          dmp[pidx]  = (pm > 0.5f) ? 0.f : 0.3f*pm;
        }
      }
    }
  }
}

// ---------------- FC1 partial GEMM -> 32 slices ----------------
__global__ void __launch_bounds__(256)
k_fc1(const float* __restrict__ X, const float* __restrict__ Wf,
      float* __restrict__ u1s){
  __shared__ __align__(16) float lds[4896];
  float* Wl = lds;
  float* Xl = lds + 32*68;
  const int tid = threadIdx.x;
  int ot = blockIdx.x & 7, ks = blockIdx.x >> 3;
  int o0 = ot*32, k0 = ks*256;
  int w_id = tid >> 6, lane = tid & 63;
  int o_l = lane & 7, bg = lane >> 3;
  float acc[4][5];
  #pragma unroll
  for(int i=0;i<4;i++)
    #pragma unroll
    for(int j=0;j<5;j++) acc[i][j]=0.f;

  for(int c=0; c<4; c++){
    int kb = k0 + c*64;
    __syncthreads();
    for(int idx=tid; idx<512; idx+=256){
      int r = idx >> 4, j = idx & 15;
      *(float4*)&Wl[r*68 + j*4] = *(const float4*)&Wf[(size_t)(o0+r)*8192 + kb + j*4];
    }
    for(int idx=tid; idx<640; idx+=256){
      int r = idx >> 4, j = idx & 15;
      float4 v = make_float4(0.f,0.f,0.f,0.f);
      if(r < NB) v = *(const float4*)&X[(size_t)r*8192 + kb + j*4];
      *(float4*)&Xl[r*68 + j*4] = v;
    }
    __syncthreads();
    #pragma unroll
    for(int c4=0; c4<4; c4++){
      int g = w_id*4 + c4;
      float4 wv[4], xv[5];
      #pragma unroll
      for(int oi=0;oi<4;oi++) wv[oi] = *(const float4*)&Wl[(o_l+8*oi)*68 + g*4];
      #pragma unroll
      for(int bi=0;bi<5;bi++) xv[bi] = *(const float4*)&Xl[(bg*5+bi)*68 + g*4];
      #pragma unroll
      for(int oi=0;oi<4;oi++)
        #pragma unroll
        for(int bi=0;bi<5;bi++)
          acc[oi][bi] += wv[oi].x*xv[bi].x + wv[oi].y*xv[bi].y
                       + wv[oi].z*xv[bi].z + wv[oi].w*xv[bi].w;
    }
  }
  __syncthreads();
  if(w_id > 0){
    float* r = lds + ((w_id-1)*64 + lane)*20;
    #pragma unroll
    for(int oi=0;oi<4;oi++)
      #pragma unroll
      for(int bi=0;bi<5;bi++) r[oi*5+bi] = acc[oi][bi];
  }
  __syncthreads();
  if(w_id == 0){
    #pragma unroll
    for(int wv=0;wv<3;wv++){
      float* r = lds + (wv*64 + lane)*20;
      #pragma unroll
      for(int oi=0;oi<4;oi++)
        #pragma unroll
        for(int bi=0;bi<5;bi++) acc[oi][bi] += r[oi*5+bi];
    }
    #pragma unroll
    for(int bi=0;bi<5;bi++){
      int b = bg*5 + bi;
      if(b < NB){
        #pragma unroll
        for(int oi=0;oi<4;oi++)
          u1s[((size_t)ks*NB + b)*256 + o0 + o_l + 8*oi] = acc[oi][bi];
      }
    }
  }
}

// ---------------- FC1-reduce + LIAF + FC2 + LIAF + accumulate ----------------
__global__ void __launch_bounds__(256)
k_fc2(const float* __restrict__ u1s, const float* __restrict__ bf1,
      const float* __restrict__ Wf2, const float* __restrict__ bf2,
      float* __restrict__ dmh1, float* __restrict__ dmh2, float* __restrict__ acc){
  __shared__ float xs[256];
  int b = blockIdx.x;
  int o = threadIdx.x;
  float u = bf1[o];
  const float* p = u1s + (size_t)b*256 + o;
  #pragma unroll
  for(int s=0;s<32;s++) u += p[(size_t)s*NB*256];
  int idx = b*256 + o;
  float mem = dmh1[idx] + u;
  float xo = mem > 0.f ? mem : 0.f;
  dmh1[idx] = (mem > 0.5f) ? 0.f : 0.3f*mem;
  xs[o] = xo;
  __syncthreads();
  int w_id = o >> 6, lane = o & 63;
  for(int oo=w_id; oo<11; oo+=4){
    const float* wr = Wf2 + oo*256;
    float s = xs[lane]*wr[lane] + xs[lane+64]*wr[lane+64]
            + xs[lane+128]*wr[lane+128] + xs[lane+192]*wr[lane+192];
    #pragma unroll
    for(int off=32; off>0; off>>=1) s += __shfl_down(s, off, 64);
    if(lane==0){
      int i2 = b*11 + oo;
      float m2 = dmh2[i2] + s + bf2[oo];
      float ov = m2 > 0.f ? m2 : 0.f;
      dmh2[i2] = (m2 > 0.5f) ? 0.f : 0.3f*m2;
      acc[i2] += ov * (1.0f/60.0f);
    }
  }
}

// ==================== launch ====================
extern "C" void kernel_launch(void* const* d_in, const int* in_sizes, int n_in,
                              void* d_out, int out_size, void* d_ws, size_t ws_size,
                              hipStream_t stream) {
  Params p;
  p.data = (const float*)d_in[0];
  p.W0  = (const float*)d_in[2];  p.b0  = (const float*)d_in[3];
  p.W1  = (const float*)d_in[4];  p.b1  = (const float*)d_in[5];
  p.W2  = (const float*)d_in[6];  p.b2  = (const float*)d_in[7];
  p.Wf1 = (const float*)d_in[8];  p.bf1 = (const float*)d_in[9];
  p.Wf2 = (const float*)d_in[10]; p.bf2 = (const float*)d_in[11];
  p.acc = (float*)d_out;

  float* ws = (float*)d_ws;
  const size_t S_XB    = (size_t)NT*NB*2*34*34;
  const size_t S_W0T   = 2*9*64;
  const size_t S_W2T   = 128*9*128;
  const size_t S_W1S   = 128*576/2;
  const size_t S_XHF   = (size_t)NB*64*34*34/2;
  const size_t S_OP1   = (size_t)NB*128*18*18;
  const size_t S_OP2   = (size_t)NB*128*8*8;
  const size_t S_U1S   = (size_t)32*NB*256;
  const size_t S_DM0   = (size_t)NB*64*34*34;
  const size_t S_DM1   = (size_t)NB*128*32*32;
  const size_t S_DMP1  = S_OP1;
  const size_t S_DM2   = (size_t)NB*128*16*16;
  const size_t S_DMP2  = S_OP2;
  const size_t S_OH1   = (size_t)NB*256;

  p.xb    = ws;  ws += S_XB;
  p.w0t   = ws;  ws += S_W0T;
  p.w2t   = ws;  ws += S_W2T;
  p.w1h   = (unsigned short*)ws;  ws += S_W1S;
  p.w1l   = (unsigned short*)ws;  ws += S_W1S;
  p.zbase = ws;
  p.xh    = (unsigned short*)ws;  ws += S_XHF;
  p.xl    = (unsigned short*)ws;  ws += S_XHF;
  p.outp1 = ws;  ws += S_OP1;
  p.outp2 = ws;  ws += S_OP2;
  p.u1s   = ws;  ws += S_U1S;
  p.dm0   = ws;  ws += S_DM0;
  p.dm1   = ws;  ws += S_DM1;
  p.dmp1  = ws;  ws += S_DMP1;
  p.dm2   = ws;  ws += S_DM2;
  p.dmp2  = ws;  ws += S_DMP2;
  p.dmh1  = ws;  ws += S_OH1;
  p.dmh2  = ws;  ws += (size_t)NB*11;
  p.zn4   = (int)((ws - p.zbase) / 4);

  k_prep<<<dim3(1024), dim3(256), 0, stream>>>(p);
  for(int t=0; t<NT; t++){
    const float* xt = p.xb + (size_t)t*NB*2*34*34;
    // conv0: 2->64 @32x32, fp32, writes bf16 hi/lo (RNE) padded (288 blocks)
    k_conv<2,64,32,8,4,1,8,0,1,0,2,1><<<dim3(288), dim3(256), 0, stream>>>(
        xt, p.w0t, p.b0, p.dm0, nullptr, nullptr, nullptr, p.xh, p.xl);
    // conv1+pool1: MFMA bf16x3 implicit GEMM (576 blocks x 256)
    k_conv1<<<dim3(576), dim3(256), 0, stream>>>(
        p.xh, p.xl, p.w1h, p.w1l, p.b1, p.dm1, p.dmp1, p.outp1);
    // conv2+pool2: fp32 R9-exact (2304 blocks x 64)
    k_conv<128,128,16,4,2,1,4,1,0,0,64,0><<<dim3(2304), dim3(64), 0, stream>>>(
        p.outp1, p.w2t, p.b2, p.dm2, nullptr, p.dmp2, p.outp2, nullptr, nullptr);
    // fc1 -> 32 slices (256 blocks)
    k_fc1<<<dim3(256), dim3(256), 0, stream>>>(p.outp2, p.Wf1, p.u1s);
    // fc1-reduce + LIAF + fc2 + LIAF + accumulate (36 blocks)
    k_fc2<<<dim3(36), dim3(256), 0, stream>>>(p.u1s, p.bf1, p.Wf2, p.bf2,
                                              p.dmh1, p.dmh2, p.acc);
  }
}

// Round 14
// 9978.163 us; speedup vs baseline: 1.8594x; 1.1177x over previous
//
#include <hip/hip_runtime.h>

#define NB 36
#define NT 60

typedef __attribute__((ext_vector_type(8))) short short8;
typedef __attribute__((ext_vector_type(4))) float f32x4;

struct Params {
  const float *data;
  const float *W0, *b0, *W1, *b1, *W2, *b2, *Wf1, *bf1, *Wf2, *bf2;
  float *xb, *w0t;
  unsigned short *w1h, *w1l, *w2h, *w2l, *xh, *xl, *p1h, *p1l;
  float *outp2, *u1s;
  float *dm0, *dm1, *dmp1, *dm2, *dmp2, *dmh1, *dmh2;
  float *acc;
  float *zbase; int zn4;
};

// round-to-nearest-even bf16 (truncation was R12's failure: one-sided residual
// accumulates linearly over K)
__device__ __forceinline__ unsigned short bf16_rne(float v){
  unsigned int bits = __float_as_uint(v);
  unsigned int r = bits + 0x7FFFu + ((bits >> 16) & 1u);
  return (unsigned short)(r >> 16);
}
__device__ __forceinline__ void bf16split(float v, unsigned short& h, unsigned short& l){
  h = bf16_rne(v);
  float hf = __uint_as_float((unsigned int)h << 16);
  l = bf16_rne(v - hf);
}

// ---------------- prep ----------------
__global__ void __launch_bounds__(256) k_prep(Params p){
  int gt  = blockIdx.x*256 + threadIdx.x;
  int STR = gridDim.x*256;
  if(gt < NB*11) p.acc[gt] = 0.f;
  for(int i=gt; i<p.zn4; i+=STR) ((float4*)p.zbase)[i] = make_float4(0.f,0.f,0.f,0.f);
  const int PLANE = 34*34;
  for(int i=gt; i<NT*NB*2*PLANE; i+=STR){
    int t   = i / (NB*2*PLANE);
    int rem = i % (NB*2*PLANE);
    int bc  = rem / PLANE;
    int pix = rem % PLANE;
    int ph = pix/34, pw = pix%34;
    float v = 0.f;
    if(ph>=1 && ph<=32 && pw>=1 && pw<=32){
      float d = p.data[((size_t)bc*1024 + (ph-1)*32 + (pw-1))*NT + t];
      v = (d > 1.0f) ? 1.0f : 0.0f;
    }
    p.xb[i] = v;
  }
  for(int i=gt; i<2*9*64; i+=STR){
    int co=i%64, rr=i/64; p.w0t[i] = p.W0[(co*2 + rr/9)*9 + rr%9];
  }
  // w1 split (RNE), layout [cout][k=cin*9+dd], K=576
  for(int i=gt; i<128*576; i+=STR){
    int co = i/576, k = i%576;
    int cin = k/9, dd = k%9;
    float v = p.W1[(co*64+cin)*9 + dd];
    unsigned short h,l; bf16split(v,h,l);
    p.w1h[i]=h; p.w1l[i]=l;
  }
  // w2 split (RNE), layout [cout][k=cin*9+dd], K=1152
  for(int i=gt; i<128*1152; i+=STR){
    int co = i/1152, k = i%1152;
    int cin = k/9, dd = k%9;
    float v = p.W2[(co*128+cin)*9 + dd];
    unsigned short h,l; bf16split(v,h,l);
    p.w2h[i]=h; p.w2l[i]=l;
  }
}

// ---------------- conv0: fp32 conv3x3 + LIAF, writes bf16 hi/lo padded ----------------
template<int Cin,int Cout,int HW,int CO,int PX,int TY,int CS>
__global__ void __launch_bounds__(HW*TY)
k_conv0(const float* __restrict__ x, const float* __restrict__ wt,
        const float* __restrict__ bias, float* __restrict__ dm,
        unsigned short* __restrict__ outh, unsigned short* __restrict__ outl)
{
  const int NCOG = Cout/CO;
  const int TH   = PX*TY;
  const int NHG  = HW/TH;
  const int NH4  = CO/4;
  const int NTHL = HW*TY;
  const int PIN  = HW+2;
  const int XR   = PX+2;
  int tile = blockIdx.x;
  int tid  = threadIdx.x;
  int cog = tile % NCOG;
  int hg  = (tile/NCOG) % NHG;
  int b   = tile/(NCOG*NHG);
  int w0  = tid % HW;
  int ty  = tid / HW;
  int h0  = hg*TH + ty*PX;

  __shared__ __align__(16) float wl[CS*9*CO];

  float accs[PX][CO];
  #pragma unroll
  for(int p=0;p<PX;p++)
    #pragma unroll
    for(int c=0;c<CO;c++) accs[p][c]=0.f;

  for(int cs=0; cs<Cin; cs+=CS){
    __syncthreads();
    for(int j=tid; j<CS*9*CO; j+=NTHL){
      int c  = j % CO;
      int rr = j / CO;
      wl[j] = wt[(cs*9 + rr)*Cout + cog*CO + c];
    }
    __syncthreads();

    for(int lc=0; lc<CS; lc++){
      const float* xc = x + ((size_t)b*Cin + cs + lc)*PIN*PIN + (size_t)h0*PIN + w0;
      float xv[XR][3];
      #pragma unroll
      for(int r=0;r<XR;r++)
        #pragma unroll
        for(int c=0;c<3;c++) xv[r][c] = xc[(size_t)r*PIN + c];
      const float4* w4 = (const float4*)(wl + lc*9*CO);
      #pragma unroll
      for(int dh=0;dh<3;dh++){
        #pragma unroll
        for(int g=0;g<NH4;g++){
          float4 wa = w4[(dh*3+0)*NH4+g];
          float4 wb = w4[(dh*3+1)*NH4+g];
          float4 wc = w4[(dh*3+2)*NH4+g];
          const float* A  = (const float*)&wa;
          const float* Bp = (const float*)&wb;
          const float* Cp = (const float*)&wc;
          #pragma unroll
          for(int cc=0;cc<4;cc++){
            #pragma unroll
            for(int px=0;px<PX;px++)
              accs[px][g*4+cc] += A[cc]*xv[px+dh][0] + Bp[cc]*xv[px+dh][1] + Cp[cc]*xv[px+dh][2];
          }
        }
      }
    }
  }

  int co0 = cog*CO;
  #pragma unroll
  for(int co=0; co<CO; co++){
    float bsv = bias[co0+co];
    const int OS = HW + 2;
    size_t plane = (size_t)(b*Cout + co0+co)*OS*OS;
    #pragma unroll
    for(int px=0; px<PX; px++){
      size_t idx = plane + (size_t)(h0+px+1)*OS + w0 + 1;
      float mem = dm[idx] + accs[px][co] + bsv;
      float ov = mem > 0.f ? mem : 0.f;
      dm[idx]  = (mem > 0.5f) ? 0.f : 0.3f*mem;
      unsigned short h,l; bf16split(ov,h,l);
      outh[idx]=h; outl[idx]=l;
    }
  }
}

// ---------------- conv1: implicit-GEMM MFMA bf16x3 + LIAF + pool -> bf16 ----------------
// Grid 576 = 36b x 2cog x 8pxg. Block 64co x 128px. K=576, 18 chunks of 32.
__global__ void __launch_bounds__(256)
k_conv1(const unsigned short* __restrict__ xh, const unsigned short* __restrict__ xl,
        const unsigned short* __restrict__ w1h, const unsigned short* __restrict__ w1l,
        const float* __restrict__ bias, float* __restrict__ dm,
        float* __restrict__ dmp, unsigned short* __restrict__ p1h,
        unsigned short* __restrict__ p1l)
{
  __shared__ unsigned short lds[15360];
  unsigned short* Ah = lds;           // 64*40
  unsigned short* Al = lds + 2560;
  unsigned short* Xh = lds + 5120;    // 128*40
  unsigned short* Xl = lds + 10240;

  int bid = blockIdx.x;
  int cog = bid & 1;
  int pxg = (bid>>1) & 7;
  int b   = bid >> 4;
  int tid = threadIdx.x;
  int wv  = tid >> 6, lane = tid & 63;
  int wm = wv & 1, wn = wv >> 1;
  int n = lane & 15, quad = lane >> 4;
  int r0 = pxg*4;

  f32x4 acc[2][4];
  #pragma unroll
  for(int mo=0;mo<2;mo++)
    #pragma unroll
    for(int no=0;no<4;no++) acc[mo][no] = (f32x4){0.f,0.f,0.f,0.f};

  int aco = tid >> 2;
  int aq  = tid & 3;
  const unsigned short* whp = w1h + (size_t)(cog*64 + aco)*576 + aq*8;
  const unsigned short* wlp = w1l + (size_t)(cog*64 + aco)*576 + aq*8;
  int sk  = tid >> 3;
  int pxq = tid & 7;
  int srow = pxq >> 1;
  int scol = (pxq & 1) * 16;
  int pxb  = pxq * 16;

  for(int ch=0; ch<18; ch++){
    int k0 = ch*32;
    __syncthreads();
    *(uint4*)&Ah[aco*40 + aq*8] = *(const uint4*)(whp + k0);
    *(uint4*)&Al[aco*40 + aq*8] = *(const uint4*)(wlp + k0);
    int kg = k0 + sk;
    int cin = kg / 9;
    int dd  = kg - cin*9;
    int dh = dd/3, dw = dd - dh*3;
    size_t soff = ((size_t)(b*64 + cin)*34 + (r0 + srow + dh))*34 + scol + dw;
    const unsigned short* sh = xh + soff;
    const unsigned short* sl = xl + soff;
    #pragma unroll
    for(int i=0;i<16;i++){
      Xh[(pxb+i)*40 + sk] = sh[i];
      Xl[(pxb+i)*40 + sk] = sl[i];
    }
    __syncthreads();

    short8 ahf[2], alf[2];
    #pragma unroll
    for(int mo=0;mo<2;mo++){
      int row = wm*32 + mo*16 + n;
      ahf[mo] = *(const short8*)&Ah[row*40 + quad*8];
      alf[mo] = *(const short8*)&Al[row*40 + quad*8];
    }
    #pragma unroll
    for(int no=0;no<4;no++){
      int prow = wn*64 + no*16 + n;
      short8 xhf = *(const short8*)&Xh[prow*40 + quad*8];
      short8 xlf = *(const short8*)&Xl[prow*40 + quad*8];
      #pragma unroll
      for(int mo=0;mo<2;mo++){
        acc[mo][no] = __builtin_amdgcn_mfma_f32_16x16x32_bf16(ahf[mo], xhf, acc[mo][no],0,0,0);
        acc[mo][no] = __builtin_amdgcn_mfma_f32_16x16x32_bf16(ahf[mo], xlf, acc[mo][no],0,0,0);
        acc[mo][no] = __builtin_amdgcn_mfma_f32_16x16x32_bf16(alf[mo], xhf, acc[mo][no],0,0,0);
      }
    }
  }

  // epilogue: LIAF (dm1 packed 32x32) + 2x2 pool -> bf16 hi/lo (18x18 padded)
  #pragma unroll
  for(int mo=0;mo<2;mo++){
    #pragma unroll
    for(int reg=0;reg<4;reg++){
      int co = cog*64 + wm*32 + mo*16 + quad*4 + reg;
      float bsv = bias[co];
      float o[4];
      #pragma unroll
      for(int no=0;no<4;no++){
        int r = r0 + wn*2 + (no>>1);
        int c = (no&1)*16 + n;
        size_t idx = (((size_t)b*128 + co)*32 + r)*32 + c;
        float mem = dm[idx] + acc[mo][no][reg] + bsv;
        o[no] = mem > 0.f ? mem : 0.f;
        dm[idx] = (mem > 0.5f) ? 0.f : 0.3f*mem;
      }
      #pragma unroll
      for(int pp=0; pp<2; pp++){
        float s = o[pp] + o[pp+2];
        s += __shfl_xor(s, 1, 64);
        if((n&1)==0){
          int pr = pxg*2 + wn;
          int pc = pp*8 + (n>>1);
          size_t pidx = (((size_t)b*128 + co)*18 + pr+1)*18 + pc+1;
          float pm = dmp[pidx] + s*0.25f;
          float pv = pm > 0.f ? pm : 0.f;
          dmp[pidx] = (pm > 0.5f) ? 0.f : 0.3f*pm;
          unsigned short h,l; bf16split(pv,h,l);
          p1h[pidx]=h; p1l[pidx]=l;
        }
      }
    }
  }
}

// ---------------- conv2: implicit-GEMM MFMA bf16x3 + LIAF + pool -> fp32 ----------------
// Grid 288 = 36b x 2cog x 4pxg. Block 64co x 64px. K=1152, 36 chunks of 32.
__global__ void __launch_bounds__(256)
k_conv2(const unsigned short* __restrict__ xh, const unsigned short* __restrict__ xl,
        const unsigned short* __restrict__ w2h, const unsigned short* __restrict__ w2l,
        const float* __restrict__ bias, float* __restrict__ dm,
        float* __restrict__ dmp, float* __restrict__ outp)
{
  __shared__ unsigned short lds[10240];
  unsigned short* Ah = lds;           // 64*40
  unsigned short* Al = lds + 2560;
  unsigned short* Xh = lds + 5120;    // 64*40
  unsigned short* Xl = lds + 7680;

  int bid = blockIdx.x;
  int cog = bid & 1;
  int pxg = (bid>>1) & 3;
  int b   = bid >> 3;
  int tid = threadIdx.x;
  int wv  = tid >> 6, lane = tid & 63;
  int wm = wv & 1, wn = wv >> 1;
  int n = lane & 15, quad = lane >> 4;
  int r0 = pxg*4;

  f32x4 acc[2][2];
  #pragma unroll
  for(int mo=0;mo<2;mo++)
    #pragma unroll
    for(int no=0;no<2;no++) acc[mo][no] = (f32x4){0.f,0.f,0.f,0.f};

  int aco = tid >> 2;
  int aq  = tid & 3;
  const unsigned short* whp = w2h + (size_t)(cog*64 + aco)*1152 + aq*8;
  const unsigned short* wlp = w2l + (size_t)(cog*64 + aco)*1152 + aq*8;
  int sk  = tid >> 3;
  int pxq = tid & 7;
  int srow = pxq >> 1;
  int scol = (pxq & 1) * 8;
  int pxb  = pxq * 8;

  for(int ch=0; ch<36; ch++){
    int k0 = ch*32;
    __syncthreads();
    *(uint4*)&Ah[aco*40 + aq*8] = *(const uint4*)(whp + k0);
    *(uint4*)&Al[aco*40 + aq*8] = *(const uint4*)(wlp + k0);
    int kg = k0 + sk;
    int cin = kg / 9;
    int dd  = kg - cin*9;
    int dh = dd/3, dw = dd - dh*3;
    size_t soff = ((size_t)(b*128 + cin)*18 + (r0 + srow + dh))*18 + scol + dw;
    const unsigned short* sh = xh + soff;
    const unsigned short* sl = xl + soff;
    #pragma unroll
    for(int i=0;i<8;i++){
      Xh[(pxb+i)*40 + sk] = sh[i];
      Xl[(pxb+i)*40 + sk] = sl[i];
    }
    __syncthreads();

    short8 ahf[2], alf[2];
    #pragma unroll
    for(int mo=0;mo<2;mo++){
      int row = wm*32 + mo*16 + n;
      ahf[mo] = *(const short8*)&Ah[row*40 + quad*8];
      alf[mo] = *(const short8*)&Al[row*40 + quad*8];
    }
    #pragma unroll
    for(int no=0;no<2;no++){
      int prow = wn*32 + no*16 + n;
      short8 xhf = *(const short8*)&Xh[prow*40 + quad*8];
      short8 xlf = *(const short8*)&Xl[prow*40 + quad*8];
      #pragma unroll
      for(int mo=0;mo<2;mo++){
        acc[mo][no] = __builtin_amdgcn_mfma_f32_16x16x32_bf16(ahf[mo], xhf, acc[mo][no],0,0,0);
        acc[mo][no] = __builtin_amdgcn_mfma_f32_16x16x32_bf16(ahf[mo], xlf, acc[mo][no],0,0,0);
        acc[mo][no] = __builtin_amdgcn_mfma_f32_16x16x32_bf16(alf[mo], xhf, acc[mo][no],0,0,0);
      }
    }
  }

  // epilogue: LIAF (dm2 packed 16x16) + 2x2 pool -> outp2 fp32 (8x8 packed)
  #pragma unroll
  for(int mo=0;mo<2;mo++){
    #pragma unroll
    for(int reg=0;reg<4;reg++){
      int co = cog*64 + wm*32 + mo*16 + quad*4 + reg;
      float bsv = bias[co];
      float o[2];
      #pragma unroll
      for(int no=0;no<2;no++){
        int r = r0 + wn*2 + no;
        int c = n;
        size_t idx = (((size_t)b*128 + co)*16 + r)*16 + c;
        float mem = dm[idx] + acc[mo][no][reg] + bsv;
        o[no] = mem > 0.f ? mem : 0.f;
        dm[idx] = (mem > 0.5f) ? 0.f : 0.3f*mem;
      }
      float s = o[0] + o[1];
      s += __shfl_xor(s, 1, 64);
      if((n&1)==0){
        int pr = pxg*2 + wn;
        int pc = n>>1;
        size_t pidx = (((size_t)b*128 + co)*8 + pr)*8 + pc;
        float pm = dmp[pidx] + s*0.25f;
        outp[pidx] = pm > 0.f ? pm : 0.f;
        dmp[pidx]  = (pm > 0.5f) ? 0.f : 0.3f*pm;
      }
    }
  }
}

// ---------------- FC1 partial GEMM -> 32 slices ----------------
__global__ void __launch_bounds__(256)
k_fc1(const float* __restrict__ X, const float* __restrict__ Wf,
      float* __restrict__ u1s){
  __shared__ __align__(16) float lds[4896];
  float* Wl = lds;
  float* Xl = lds + 32*68;
  const int tid = threadIdx.x;
  int ot = blockIdx.x & 7, ks = blockIdx.x >> 3;
  int o0 = ot*32, k0 = ks*256;
  int w_id = tid >> 6, lane = tid & 63;
  int o_l = lane & 7, bg = lane >> 3;
  float acc[4][5];
  #pragma unroll
  for(int i=0;i<4;i++)
    #pragma unroll
    for(int j=0;j<5;j++) acc[i][j]=0.f;

  for(int c=0; c<4; c++){
    int kb = k0 + c*64;
    __syncthreads();
    for(int idx=tid; idx<512; idx+=256){
      int r = idx >> 4, j = idx & 15;
      *(float4*)&Wl[r*68 + j*4] = *(const float4*)&Wf[(size_t)(o0+r)*8192 + kb + j*4];
    }
    for(int idx=tid; idx<640; idx+=256){
      int r = idx >> 4, j = idx & 15;
      float4 v = make_float4(0.f,0.f,0.f,0.f);
      if(r < NB) v = *(const float4*)&X[(size_t)r*8192 + kb + j*4];
      *(float4*)&Xl[r*68 + j*4] = v;
    }
    __syncthreads();
    #pragma unroll
    for(int c4=0; c4<4; c4++){
      int g = w_id*4 + c4;
      float4 wv[4], xv[5];
      #pragma unroll
      for(int oi=0;oi<4;oi++) wv[oi] = *(const float4*)&Wl[(o_l+8*oi)*68 + g*4];
      #pragma unroll
      for(int bi=0;bi<5;bi++) xv[bi] = *(const float4*)&Xl[(bg*5+bi)*68 + g*4];
      #pragma unroll
      for(int oi=0;oi<4;oi++)
        #pragma unroll
        for(int bi=0;bi<5;bi++)
          acc[oi][bi] += wv[oi].x*xv[bi].x + wv[oi].y*xv[bi].y
                       + wv[oi].z*xv[bi].z + wv[oi].w*xv[bi].w;
    }
  }
  __syncthreads();
  if(w_id > 0){
    float* r = lds + ((w_id-1)*64 + lane)*20;
    #pragma unroll
    for(int oi=0;oi<4;oi++)
      #pragma unroll
      for(int bi=0;bi<5;bi++) r[oi*5+bi] = acc[oi][bi];
  }
  __syncthreads();
  if(w_id == 0){
    #pragma unroll
    for(int wv=0;wv<3;wv++){
      float* r = lds + (wv*64 + lane)*20;
      #pragma unroll
      for(int oi=0;oi<4;oi++)
        #pragma unroll
        for(int bi=0;bi<5;bi++) acc[oi][bi] += r[oi*5+bi];
    }
    #pragma unroll
    for(int bi=0;bi<5;bi++){
      int b = bg*5 + bi;
      if(b < NB){
        #pragma unroll
        for(int oi=0;oi<4;oi++)
          u1s[((size_t)ks*NB + b)*256 + o0 + o_l + 8*oi] = acc[oi][bi];
      }
    }
  }
}

// ---------------- FC1-reduce + LIAF + FC2 + LIAF + accumulate ----------------
__global__ void __launch_bounds__(256)
k_fc2(const float* __restrict__ u1s, const float* __restrict__ bf1,
      const float* __restrict__ Wf2, const float* __restrict__ bf2,
      float* __restrict__ dmh1, float* __restrict__ dmh2, float* __restrict__ acc){
  __shared__ float xs[256];
  int b = blockIdx.x;
  int o = threadIdx.x;
  float u = bf1[o];
  const float* p = u1s + (size_t)b*256 + o;
  #pragma unroll
  for(int s=0;s<32;s++) u += p[(size_t)s*NB*256];
  int idx = b*256 + o;
  float mem = dmh1[idx] + u;
  float xo = mem > 0.f ? mem : 0.f;
  dmh1[idx] = (mem > 0.5f) ? 0.f : 0.3f*mem;
  xs[o] = xo;
  __syncthreads();
  int w_id = o >> 6, lane = o & 63;
  for(int oo=w_id; oo<11; oo+=4){
    const float* wr = Wf2 + oo*256;
    float s = xs[lane]*wr[lane] + xs[lane+64]*wr[lane+64]
            + xs[lane+128]*wr[lane+128] + xs[lane+192]*wr[lane+192];
    #pragma unroll
    for(int off=32; off>0; off>>=1) s += __shfl_down(s, off, 64);
    if(lane==0){
      int i2 = b*11 + oo;
      float m2 = dmh2[i2] + s + bf2[oo];
      float ov = m2 > 0.f ? m2 : 0.f;
      dmh2[i2] = (m2 > 0.5f) ? 0.f : 0.3f*m2;
      acc[i2] += ov * (1.0f/60.0f);
    }
  }
}

// ==================== launch ====================
extern "C" void kernel_launch(void* const* d_in, const int* in_sizes, int n_in,
                              void* d_out, int out_size, void* d_ws, size_t ws_size,
                              hipStream_t stream) {
  Params p;
  p.data = (const float*)d_in[0];
  p.W0  = (const float*)d_in[2];  p.b0  = (const float*)d_in[3];
  p.W1  = (const float*)d_in[4];  p.b1  = (const float*)d_in[5];
  p.W2  = (const float*)d_in[6];  p.b2  = (const float*)d_in[7];
  p.Wf1 = (const float*)d_in[8];  p.bf1 = (const float*)d_in[9];
  p.Wf2 = (const float*)d_in[10]; p.bf2 = (const float*)d_in[11];
  p.acc = (float*)d_out;

  float* ws = (float*)d_ws;
  const size_t S_XB    = (size_t)NT*NB*2*34*34;
  const size_t S_W0T   = 2*9*64;
  const size_t S_W1S   = 128*576/2;               // ushort in float units
  const size_t S_W2S   = 128*1152/2;
  const size_t S_XHF   = (size_t)NB*64*34*34/2;   // bf16 x, padded
  const size_t S_P1S   = (size_t)NB*128*18*18/2;  // bf16 pooled1, padded
  const size_t S_OP2   = (size_t)NB*128*8*8;
  const size_t S_U1S   = (size_t)32*NB*256;
  const size_t S_DM0   = (size_t)NB*64*34*34;
  const size_t S_DM1   = (size_t)NB*128*32*32;
  const size_t S_DMP1  = (size_t)NB*128*18*18;
  const size_t S_DM2   = (size_t)NB*128*16*16;
  const size_t S_DMP2  = S_OP2;
  const size_t S_OH1   = (size_t)NB*256;

  p.xb    = ws;  ws += S_XB;
  p.w0t   = ws;  ws += S_W0T;
  p.w1h   = (unsigned short*)ws;  ws += S_W1S;
  p.w1l   = (unsigned short*)ws;  ws += S_W1S;
  p.w2h   = (unsigned short*)ws;  ws += S_W2S;
  p.w2l   = (unsigned short*)ws;  ws += S_W2S;
  p.zbase = ws;
  p.xh    = (unsigned short*)ws;  ws += S_XHF;
  p.xl    = (unsigned short*)ws;  ws += S_XHF;
  p.p1h   = (unsigned short*)ws;  ws += S_P1S;
  p.p1l   = (unsigned short*)ws;  ws += S_P1S;
  p.outp2 = ws;  ws += S_OP2;
  p.u1s   = ws;  ws += S_U1S;
  p.dm0   = ws;  ws += S_DM0;
  p.dm1   = ws;  ws += S_DM1;
  p.dmp1  = ws;  ws += S_DMP1;
  p.dm2   = ws;  ws += S_DM2;
  p.dmp2  = ws;  ws += S_DMP2;
  p.dmh1  = ws;  ws += S_OH1;
  p.dmh2  = ws;  ws += (size_t)NB*11;
  p.zn4   = (int)((ws - p.zbase) / 4);

  k_prep<<<dim3(1024), dim3(256), 0, stream>>>(p);
  for(int t=0; t<NT; t++){
    const float* xt = p.xb + (size_t)t*NB*2*34*34;
    // conv0: 2->64 @32x32, fp32, bf16 hi/lo out (288 blocks)
    k_conv0<2,64,32,8,4,8,2><<<dim3(288), dim3(256), 0, stream>>>(
        xt, p.w0t, p.b0, p.dm0, p.xh, p.xl);
    // conv1+pool1: MFMA bf16x3 (576 blocks)
    k_conv1<<<dim3(576), dim3(256), 0, stream>>>(
        p.xh, p.xl, p.w1h, p.w1l, p.b1, p.dm1, p.dmp1, p.p1h, p.p1l);
    // conv2+pool2: MFMA bf16x3 (288 blocks)
    k_conv2<<<dim3(288), dim3(256), 0, stream>>>(
        p.p1h, p.p1l, p.w2h, p.w2l, p.b2, p.dm2, p.dmp2, p.outp2);
    // fc1 -> 32 slices (256 blocks)
    k_fc1<<<dim3(256), dim3(256), 0, stream>>>(p.outp2, p.Wf1, p.u1s);
    // fc1-reduce + LIAF + fc2 + LIAF + accumulate (36 blocks)
    k_fc2<<<dim3(36), dim3(256), 0, stream>>>(p.u1s, p.bf1, p.Wf2, p.bf2,
                                              p.dmh1, p.dmh2, p.acc);
  }
}

// Round 15
// 7760.001 us; speedup vs baseline: 2.3909x; 1.2858x over previous
//
#include <hip/hip_runtime.h>

#define NB 36
#define NT 60

typedef __attribute__((ext_vector_type(8))) short short8;
typedef __attribute__((ext_vector_type(4))) float f32x4;

struct Params {
  const float *data;
  const float *W0, *b0, *W1, *b1, *W2, *b2, *Wf1, *bf1, *Wf2, *bf2;
  float *xb, *w0t;
  unsigned short *w1h, *w1l, *w2h, *w2l;
  unsigned int *xhl, *p1hl;
  float *outp2, *u1s;
  float *dm0, *dm1, *dmp1, *dm2, *dmp2, *dmh1, *dmh2;
  float *acc;
  float *zbase; int zn4;
};

// round-to-nearest-even bf16 (truncation was R12's failure: one-sided residual
// accumulates linearly over K)
__device__ __forceinline__ unsigned short bf16_rne(float v){
  unsigned int bits = __float_as_uint(v);
  unsigned int r = bits + 0x7FFFu + ((bits >> 16) & 1u);
  return (unsigned short)(r >> 16);
}
__device__ __forceinline__ unsigned int bf16pack(float v){
  unsigned short h = bf16_rne(v);
  float hf = __uint_as_float((unsigned int)h << 16);
  unsigned short l = bf16_rne(v - hf);
  return (unsigned int)h | ((unsigned int)l << 16);
}
// extract hi/lo bf16 frag from 8 packed uints in LDS
__device__ __forceinline__ void unpack8(const unsigned int* q, short8& h8, short8& l8){
  unsigned int u[8];
  *(uint4*)&u[0] = *(const uint4*)q;
  *(uint4*)&u[4] = *(const uint4*)(q+4);
  #pragma unroll
  for(int i=0;i<8;i++){
    h8[i] = (short)(u[i] & 0xffffu);
    l8[i] = (short)(u[i] >> 16);
  }
}

// ---------------- prep ----------------
__global__ void __launch_bounds__(256) k_prep(Params p){
  int gt  = blockIdx.x*256 + threadIdx.x;
  int STR = gridDim.x*256;
  if(gt < NB*11) p.acc[gt] = 0.f;
  for(int i=gt; i<p.zn4; i+=STR) ((float4*)p.zbase)[i] = make_float4(0.f,0.f,0.f,0.f);
  const int PLANE = 34*34;
  for(int i=gt; i<NT*NB*2*PLANE; i+=STR){
    int t   = i / (NB*2*PLANE);
    int rem = i % (NB*2*PLANE);
    int bc  = rem / PLANE;
    int pix = rem % PLANE;
    int ph = pix/34, pw = pix%34;
    float v = 0.f;
    if(ph>=1 && ph<=32 && pw>=1 && pw<=32){
      float d = p.data[((size_t)bc*1024 + (ph-1)*32 + (pw-1))*NT + t];
      v = (d > 1.0f) ? 1.0f : 0.0f;
    }
    p.xb[i] = v;
  }
  for(int i=gt; i<2*9*64; i+=STR){
    int co=i%64, rr=i/64; p.w0t[i] = p.W0[(co*2 + rr/9)*9 + rr%9];
  }
  // w1 split (RNE), layout [cout][k=cin*9+dd], K=576
  for(int i=gt; i<128*576; i+=STR){
    int co = i/576, k = i%576;
    int cin = k/9, dd = k%9;
    unsigned int pk = bf16pack(p.W1[(co*64+cin)*9 + dd]);
    p.w1h[i]=(unsigned short)(pk&0xffffu); p.w1l[i]=(unsigned short)(pk>>16);
  }
  // w2 split (RNE), layout [cout][k=cin*9+dd], K=1152
  for(int i=gt; i<128*1152; i+=STR){
    int co = i/1152, k = i%1152;
    int cin = k/9, dd = k%9;
    unsigned int pk = bf16pack(p.W2[(co*128+cin)*9 + dd]);
    p.w2h[i]=(unsigned short)(pk&0xffffu); p.w2l[i]=(unsigned short)(pk>>16);
  }
}

// ---------------- conv0: fp32 conv3x3 + LIAF, writes packed bf16 hi|lo ----------------
template<int Cin,int Cout,int HW,int CO,int PX,int TY,int CS>
__global__ void __launch_bounds__(HW*TY)
k_conv0(const float* __restrict__ x, const float* __restrict__ wt,
        const float* __restrict__ bias, float* __restrict__ dm,
        unsigned int* __restrict__ outhl)
{
  const int NCOG = Cout/CO;
  const int TH   = PX*TY;
  const int NHG  = HW/TH;
  const int NH4  = CO/4;
  const int NTHL = HW*TY;
  const int PIN  = HW+2;
  const int XR   = PX+2;
  int tile = blockIdx.x;
  int tid  = threadIdx.x;
  int cog = tile % NCOG;
  int hg  = (tile/NCOG) % NHG;
  int b   = tile/(NCOG*NHG);
  int w0  = tid % HW;
  int ty  = tid / HW;
  int h0  = hg*TH + ty*PX;

  __shared__ __align__(16) float wl[CS*9*CO];

  float accs[PX][CO];
  #pragma unroll
  for(int p=0;p<PX;p++)
    #pragma unroll
    for(int c=0;c<CO;c++) accs[p][c]=0.f;

  for(int cs=0; cs<Cin; cs+=CS){
    __syncthreads();
    for(int j=tid; j<CS*9*CO; j+=NTHL){
      int c  = j % CO;
      int rr = j / CO;
      wl[j] = wt[(cs*9 + rr)*Cout + cog*CO + c];
    }
    __syncthreads();

    for(int lc=0; lc<CS; lc++){
      const float* xc = x + ((size_t)b*Cin + cs + lc)*PIN*PIN + (size_t)h0*PIN + w0;
      float xv[XR][3];
      #pragma unroll
      for(int r=0;r<XR;r++)
        #pragma unroll
        for(int c=0;c<3;c++) xv[r][c] = xc[(size_t)r*PIN + c];
      const float4* w4 = (const float4*)(wl + lc*9*CO);
      #pragma unroll
      for(int dh=0;dh<3;dh++){
        #pragma unroll
        for(int g=0;g<NH4;g++){
          float4 wa = w4[(dh*3+0)*NH4+g];
          float4 wb = w4[(dh*3+1)*NH4+g];
          float4 wc = w4[(dh*3+2)*NH4+g];
          const float* A  = (const float*)&wa;
          const float* Bp = (const float*)&wb;
          const float* Cp = (const float*)&wc;
          #pragma unroll
          for(int cc=0;cc<4;cc++){
            #pragma unroll
            for(int px=0;px<PX;px++)
              accs[px][g*4+cc] += A[cc]*xv[px+dh][0] + Bp[cc]*xv[px+dh][1] + Cp[cc]*xv[px+dh][2];
          }
        }
      }
    }
  }

  int co0 = cog*CO;
  #pragma unroll
  for(int co=0; co<CO; co++){
    float bsv = bias[co0+co];
    const int OS = HW + 2;
    size_t plane = (size_t)(b*Cout + co0+co)*OS*OS;
    #pragma unroll
    for(int px=0; px<PX; px++){
      size_t idx = plane + (size_t)(h0+px+1)*OS + w0 + 1;
      float mem = dm[idx] + accs[px][co] + bsv;
      float ov = mem > 0.f ? mem : 0.f;
      dm[idx]  = (mem > 0.5f) ? 0.f : 0.3f*mem;
      outhl[idx] = bf16pack(ov);
    }
  }
}

// ---------------- conv1: implicit-GEMM MFMA bf16x3 + LIAF + pool -> packed bf16 ----------------
// Grid 576 = 36b x 2cog x 8pxg. Block 64co x 128px. K=576, 18 chunks of 32.
// X staged as packed uints, pitch 44 (2-way-free banks); A split h/l pitch 40.
__global__ void __launch_bounds__(256)
k_conv1(const unsigned int* __restrict__ xhl,
        const unsigned short* __restrict__ w1h, const unsigned short* __restrict__ w1l,
        const float* __restrict__ bias, float* __restrict__ dm,
        float* __restrict__ dmp, unsigned int* __restrict__ p1hl)
{
  __shared__ __align__(16) unsigned int ldsu[8192];   // 32 KB
  unsigned short* Ah = (unsigned short*)ldsu;          // 64*40 ushorts
  unsigned short* Al = (unsigned short*)(ldsu + 1280);
  unsigned int*   Xp = ldsu + 2560;                    // 128*44 uints

  int bid = blockIdx.x;
  int cog = bid & 1;
  int pxg = (bid>>1) & 7;
  int b   = bid >> 4;
  int tid = threadIdx.x;
  int wv  = tid >> 6, lane = tid & 63;
  int wm = wv & 1, wn = wv >> 1;
  int n = lane & 15, quad = lane >> 4;
  int r0 = pxg*4;

  f32x4 acc[2][4];
  #pragma unroll
  for(int mo=0;mo<2;mo++)
    #pragma unroll
    for(int no=0;no<4;no++) acc[mo][no] = (f32x4){0.f,0.f,0.f,0.f};

  int aco = tid >> 2;
  int aq  = tid & 3;
  const unsigned short* whp = w1h + (size_t)(cog*64 + aco)*576 + aq*8;
  const unsigned short* wlp = w1l + (size_t)(cog*64 + aco)*576 + aq*8;
  int sk  = tid >> 3;
  int pxq = tid & 7;
  int srow = pxq >> 1;
  int scol = (pxq & 1) * 16;
  int pxb  = pxq * 16;

  for(int ch=0; ch<18; ch++){
    int k0 = ch*32;
    __syncthreads();
    *(uint4*)&Ah[aco*40 + aq*8] = *(const uint4*)(whp + k0);
    *(uint4*)&Al[aco*40 + aq*8] = *(const uint4*)(wlp + k0);
    int kg = k0 + sk;
    int cin = kg / 9;
    int dd  = kg - cin*9;
    int dh = dd/3, dw = dd - dh*3;
    size_t soff = ((size_t)(b*64 + cin)*34 + (r0 + srow + dh))*34 + scol + dw;
    const unsigned int* sx = xhl + soff;
    unsigned int tmp[16];
    #pragma unroll
    for(int i=0;i<16;i++) tmp[i] = sx[i];
    #pragma unroll
    for(int i=0;i<16;i++) Xp[(pxb+i)*44 + sk] = tmp[i];
    __syncthreads();

    short8 ahf[2], alf[2];
    #pragma unroll
    for(int mo=0;mo<2;mo++){
      int row = wm*32 + mo*16 + n;
      ahf[mo] = *(const short8*)&Ah[row*40 + quad*8];
      alf[mo] = *(const short8*)&Al[row*40 + quad*8];
    }
    #pragma unroll
    for(int no=0;no<4;no++){
      int prow = wn*64 + no*16 + n;
      short8 xhf, xlf;
      unpack8(&Xp[prow*44 + quad*8], xhf, xlf);
      #pragma unroll
      for(int mo=0;mo<2;mo++){
        acc[mo][no] = __builtin_amdgcn_mfma_f32_16x16x32_bf16(ahf[mo], xhf, acc[mo][no],0,0,0);
        acc[mo][no] = __builtin_amdgcn_mfma_f32_16x16x32_bf16(ahf[mo], xlf, acc[mo][no],0,0,0);
        acc[mo][no] = __builtin_amdgcn_mfma_f32_16x16x32_bf16(alf[mo], xhf, acc[mo][no],0,0,0);
      }
    }
  }

  // epilogue: LIAF (dm1 packed 32x32) + 2x2 pool -> packed bf16 (18x18 padded)
  #pragma unroll
  for(int mo=0;mo<2;mo++){
    #pragma unroll
    for(int reg=0;reg<4;reg++){
      int co = cog*64 + wm*32 + mo*16 + quad*4 + reg;
      float bsv = bias[co];
      float o[4];
      #pragma unroll
      for(int no=0;no<4;no++){
        int r = r0 + wn*2 + (no>>1);
        int c = (no&1)*16 + n;
        size_t idx = (((size_t)b*128 + co)*32 + r)*32 + c;
        float mem = dm[idx] + acc[mo][no][reg] + bsv;
        o[no] = mem > 0.f ? mem : 0.f;
        dm[idx] = (mem > 0.5f) ? 0.f : 0.3f*mem;
      }
      #pragma unroll
      for(int pp=0; pp<2; pp++){
        float s = o[pp] + o[pp+2];
        s += __shfl_xor(s, 1, 64);
        if((n&1)==0){
          int pr = pxg*2 + wn;
          int pc = pp*8 + (n>>1);
          size_t pidx = (((size_t)b*128 + co)*18 + pr+1)*18 + pc+1;
          float pm = dmp[pidx] + s*0.25f;
          float pv = pm > 0.f ? pm : 0.f;
          dmp[pidx] = (pm > 0.5f) ? 0.f : 0.3f*pm;
          p1hl[pidx] = bf16pack(pv);
        }
      }
    }
  }
}

// ---------------- conv2: implicit-GEMM MFMA bf16x3 + LIAF + pool -> fp32 ----------------
// Grid 288 = 36b x 2cog x 4pxg. Block 64co x 64px. K=1152, 36 chunks of 32.
__global__ void __launch_bounds__(256)
k_conv2(const unsigned int* __restrict__ xhl,
        const unsigned short* __restrict__ w2h, const unsigned short* __restrict__ w2l,
        const float* __restrict__ bias, float* __restrict__ dm,
        float* __restrict__ dmp, float* __restrict__ outp)
{
  __shared__ __align__(16) unsigned int ldsu[5376];   // 21 KB
  unsigned short* Ah = (unsigned short*)ldsu;          // 64*40
  unsigned short* Al = (unsigned short*)(ldsu + 1280);
  unsigned int*   Xp = ldsu + 2560;                    // 64*44 uints

  int bid = blockIdx.x;
  int cog = bid & 1;
  int pxg = (bid>>1) & 3;
  int b   = bid >> 3;
  int tid = threadIdx.x;
  int wv  = tid >> 6, lane = tid & 63;
  int wm = wv & 1, wn = wv >> 1;
  int n = lane & 15, quad = lane >> 4;
  int r0 = pxg*4;

  f32x4 acc[2][2];
  #pragma unroll
  for(int mo=0;mo<2;mo++)
    #pragma unroll
    for(int no=0;no<2;no++) acc[mo][no] = (f32x4){0.f,0.f,0.f,0.f};

  int aco = tid >> 2;
  int aq  = tid & 3;
  const unsigned short* whp = w2h + (size_t)(cog*64 + aco)*1152 + aq*8;
  const unsigned short* wlp = w2l + (size_t)(cog*64 + aco)*1152 + aq*8;
  int sk  = tid >> 3;
  int pxq = tid & 7;
  int srow = pxq >> 1;
  int scol = (pxq & 1) * 8;
  int pxb  = pxq * 8;

  for(int ch=0; ch<36; ch++){
    int k0 = ch*32;
    __syncthreads();
    *(uint4*)&Ah[aco*40 + aq*8] = *(const uint4*)(whp + k0);
    *(uint4*)&Al[aco*40 + aq*8] = *(const uint4*)(wlp + k0);
    int kg = k0 + sk;
    int cin = kg / 9;
    int dd  = kg - cin*9;
    int dh = dd/3, dw = dd - dh*3;
    size_t soff = ((size_t)(b*128 + cin)*18 + (r0 + srow + dh))*18 + scol + dw;
    const unsigned int* sx = xhl + soff;
    unsigned int tmp[8];
    #pragma unroll
    for(int i=0;i<8;i++) tmp[i] = sx[i];
    #pragma unroll
    for(int i=0;i<8;i++) Xp[(pxb+i)*44 + sk] = tmp[i];
    __syncthreads();

    short8 ahf[2], alf[2];
    #pragma unroll
    for(int mo=0;mo<2;mo++){
      int row = wm*32 + mo*16 + n;
      ahf[mo] = *(const short8*)&Ah[row*40 + quad*8];
      alf[mo] = *(const short8*)&Al[row*40 + quad*8];
    }
    #pragma unroll
    for(int no=0;no<2;no++){
      int prow = wn*32 + no*16 + n;
      short8 xhf, xlf;
      unpack8(&Xp[prow*44 + quad*8], xhf, xlf);
      #pragma unroll
      for(int mo=0;mo<2;mo++){
        acc[mo][no] = __builtin_amdgcn_mfma_f32_16x16x32_bf16(ahf[mo], xhf, acc[mo][no],0,0,0);
        acc[mo][no] = __builtin_amdgcn_mfma_f32_16x16x32_bf16(ahf[mo], xlf, acc[mo][no],0,0,0);
        acc[mo][no] = __builtin_amdgcn_mfma_f32_16x16x32_bf16(alf[mo], xhf, acc[mo][no],0,0,0);
      }
    }
  }

  // epilogue: LIAF (dm2 packed 16x16) + 2x2 pool -> outp2 fp32 (8x8 packed)
  #pragma unroll
  for(int mo=0;mo<2;mo++){
    #pragma unroll
    for(int reg=0;reg<4;reg++){
      int co = cog*64 + wm*32 + mo*16 + quad*4 + reg;
      float bsv = bias[co];
      float o[2];
      #pragma unroll
      for(int no=0;no<2;no++){
        int r = r0 + wn*2 + no;
        int c = n;
        size_t idx = (((size_t)b*128 + co)*16 + r)*16 + c;
        float mem = dm[idx] + acc[mo][no][reg] + bsv;
        o[no] = mem > 0.f ? mem : 0.f;
        dm[idx] = (mem > 0.5f) ? 0.f : 0.3f*mem;
      }
      float s = o[0] + o[1];
      s += __shfl_xor(s, 1, 64);
      if((n&1)==0){
        int pr = pxg*2 + wn;
        int pc = n>>1;
        size_t pidx = (((size_t)b*128 + co)*8 + pr)*8 + pc;
        float pm = dmp[pidx] + s*0.25f;
        outp[pidx] = pm > 0.f ? pm : 0.f;
        dmp[pidx]  = (pm > 0.5f) ? 0.f : 0.3f*pm;
      }
    }
  }
}

// ---------------- FC1 partial GEMM -> 32 slices ----------------
__global__ void __launch_bounds__(256)
k_fc1(const float* __restrict__ X, const float* __restrict__ Wf,
      float* __restrict__ u1s){
  __shared__ __align__(16) float lds[4896];
  float* Wl = lds;
  float* Xl = lds + 32*68;
  const int tid = threadIdx.x;
  int ot = blockIdx.x & 7, ks = blockIdx.x >> 3;
  int o0 = ot*32, k0 = ks*256;
  int w_id = tid >> 6, lane = tid & 63;
  int o_l = lane & 7, bg = lane >> 3;
  float acc[4][5];
  #pragma unroll
  for(int i=0;i<4;i++)
    #pragma unroll
    for(int j=0;j<5;j++) acc[i][j]=0.f;

  for(int c=0; c<4; c++){
    int kb = k0 + c*64;
    __syncthreads();
    for(int idx=tid; idx<512; idx+=256){
      int r = idx >> 4, j = idx & 15;
      *(float4*)&Wl[r*68 + j*4] = *(const float4*)&Wf[(size_t)(o0+r)*8192 + kb + j*4];
    }
    for(int idx=tid; idx<640; idx+=256){
      int r = idx >> 4, j = idx & 15;
      float4 v = make_float4(0.f,0.f,0.f,0.f);
      if(r < NB) v = *(const float4*)&X[(size_t)r*8192 + kb + j*4];
      *(float4*)&Xl[r*68 + j*4] = v;
    }
    __syncthreads();
    #pragma unroll
    for(int c4=0; c4<4; c4++){
      int g = w_id*4 + c4;
      float4 wv[4], xv[5];
      #pragma unroll
      for(int oi=0;oi<4;oi++) wv[oi] = *(const float4*)&Wl[(o_l+8*oi)*68 + g*4];
      #pragma unroll
      for(int bi=0;bi<5;bi++) xv[bi] = *(const float4*)&Xl[(bg*5+bi)*68 + g*4];
      #pragma unroll
      for(int oi=0;oi<4;oi++)
        #pragma unroll
        for(int bi=0;bi<5;bi++)
          acc[oi][bi] += wv[oi].x*xv[bi].x + wv[oi].y*xv[bi].y
                       + wv[oi].z*xv[bi].z + wv[oi].w*xv[bi].w;
    }
  }
  __syncthreads();
  if(w_id > 0){
    float* r = lds + ((w_id-1)*64 + lane)*20;
    #pragma unroll
    for(int oi=0;oi<4;oi++)
      #pragma unroll
      for(int bi=0;bi<5;bi++) r[oi*5+bi] = acc[oi][bi];
  }
  __syncthreads();
  if(w_id == 0){
    #pragma unroll
    for(int wv=0;wv<3;wv++){
      float* r = lds + (wv*64 + lane)*20;
      #pragma unroll
      for(int oi=0;oi<4;oi++)
        #pragma unroll
        for(int bi=0;bi<5;bi++) acc[oi][bi] += r[oi*5+bi];
    }
    #pragma unroll
    for(int bi=0;bi<5;bi++){
      int b = bg*5 + bi;
      if(b < NB){
        #pragma unroll
        for(int oi=0;oi<4;oi++)
          u1s[((size_t)ks*NB + b)*256 + o0 + o_l + 8*oi] = acc[oi][bi];
      }
    }
  }
}

// ---------------- FC1-reduce + LIAF + FC2 + LIAF + accumulate ----------------
__global__ void __launch_bounds__(256)
k_fc2(const float* __restrict__ u1s, const float* __restrict__ bf1,
      const float* __restrict__ Wf2, const float* __restrict__ bf2,
      float* __restrict__ dmh1, float* __restrict__ dmh2, float* __restrict__ acc){
  __shared__ float xs[256];
  int b = blockIdx.x;
  int o = threadIdx.x;
  float u = bf1[o];
  const float* p = u1s + (size_t)b*256 + o;
  #pragma unroll
  for(int s=0;s<32;s++) u += p[(size_t)s*NB*256];
  int idx = b*256 + o;
  float mem = dmh1[idx] + u;
  float xo = mem > 0.f ? mem : 0.f;
  dmh1[idx] = (mem > 0.5f) ? 0.f : 0.3f*mem;
  xs[o] = xo;
  __syncthreads();
  int w_id = o >> 6, lane = o & 63;
  for(int oo=w_id; oo<11; oo+=4){
    const float* wr = Wf2 + oo*256;
    float s = xs[lane]*wr[lane] + xs[lane+64]*wr[lane+64]
            + xs[lane+128]*wr[lane+128] + xs[lane+192]*wr[lane+192];
    #pragma unroll
    for(int off=32; off>0; off>>=1) s += __shfl_down(s, off, 64);
    if(lane==0){
      int i2 = b*11 + oo;
      float m2 = dmh2[i2] + s + bf2[oo];
      float ov = m2 > 0.f ? m2 : 0.f;
      dmh2[i2] = (m2 > 0.5f) ? 0.f : 0.3f*m2;
      acc[i2] += ov * (1.0f/60.0f);
    }
  }
}

// ==================== launch ====================
extern "C" void kernel_launch(void* const* d_in, const int* in_sizes, int n_in,
                              void* d_out, int out_size, void* d_ws, size_t ws_size,
                              hipStream_t stream) {
  Params p;
  p.data = (const float*)d_in[0];
  p.W0  = (const float*)d_in[2];  p.b0  = (const float*)d_in[3];
  p.W1  = (const float*)d_in[4];  p.b1  = (const float*)d_in[5];
  p.W2  = (const float*)d_in[6];  p.b2  = (const float*)d_in[7];
  p.Wf1 = (const float*)d_in[8];  p.bf1 = (const float*)d_in[9];
  p.Wf2 = (const float*)d_in[10]; p.bf2 = (const float*)d_in[11];
  p.acc = (float*)d_out;

  float* ws = (float*)d_ws;
  const size_t S_XB    = (size_t)NT*NB*2*34*34;
  const size_t S_W0T   = 2*9*64;
  const size_t S_W1S   = 128*576/2;               // ushort arrays in float units
  const size_t S_W2S   = 128*1152/2;
  const size_t S_XHL   = (size_t)NB*64*34*34;     // packed uint, padded
  const size_t S_P1HL  = (size_t)NB*128*18*18;    // packed uint, padded
  const size_t S_OP2   = (size_t)NB*128*8*8;
  const size_t S_U1S   = (size_t)32*NB*256;
  const size_t S_DM0   = (size_t)NB*64*34*34;
  const size_t S_DM1   = (size_t)NB*128*32*32;
  const size_t S_DMP1  = (size_t)NB*128*18*18;
  const size_t S_DM2   = (size_t)NB*128*16*16;
  const size_t S_DMP2  = S_OP2;
  const size_t S_OH1   = (size_t)NB*256;

  p.xb    = ws;  ws += S_XB;
  p.w0t   = ws;  ws += S_W0T;
  p.w1h   = (unsigned short*)ws;  ws += S_W1S;
  p.w1l   = (unsigned short*)ws;  ws += S_W1S;
  p.w2h   = (unsigned short*)ws;  ws += S_W2S;
  p.w2l   = (unsigned short*)ws;  ws += S_W2S;
  p.zbase = ws;
  p.xhl   = (unsigned int*)ws;    ws += S_XHL;
  p.p1hl  = (unsigned int*)ws;    ws += S_P1HL;
  p.outp2 = ws;  ws += S_OP2;
  p.u1s   = ws;  ws += S_U1S;
  p.dm0   = ws;  ws += S_DM0;
  p.dm1   = ws;  ws += S_DM1;
  p.dmp1  = ws;  ws += S_DMP1;
  p.dm2   = ws;  ws += S_DM2;
  p.dmp2  = ws;  ws += S_DMP2;
  p.dmh1  = ws;  ws += S_OH1;
  p.dmh2  = ws;  ws += (size_t)NB*11;
  p.zn4   = (int)((ws - p.zbase) / 4);

  k_prep<<<dim3(1024), dim3(256), 0, stream>>>(p);
  for(int t=0; t<NT; t++){
    const float* xt = p.xb + (size_t)t*NB*2*34*34;
    // conv0: 2->64 @32x32, fp32, packed bf16 out (288 blocks)
    k_conv0<2,64,32,8,4,8,2><<<dim3(288), dim3(256), 0, stream>>>(
        xt, p.w0t, p.b0, p.dm0, p.xhl);
    // conv1+pool1: MFMA bf16x3, packed staging (576 blocks)
    k_conv1<<<dim3(576), dim3(256), 0, stream>>>(
        p.xhl, p.w1h, p.w1l, p.b1, p.dm1, p.dmp1, p.p1hl);
    // conv2+pool2: MFMA bf16x3, packed staging (288 blocks)
    k_conv2<<<dim3(288), dim3(256), 0, stream>>>(
        p.p1hl, p.w2h, p.w2l, p.b2, p.dm2, p.dmp2, p.outp2);
    // fc1 -> 32 slices (256 blocks)
    k_fc1<<<dim3(256), dim3(256), 0, stream>>>(p.outp2, p.Wf1, p.u1s);
    // fc1-reduce + LIAF + fc2 + LIAF + accumulate (36 blocks)
    k_fc2<<<dim3(36), dim3(256), 0, stream>>>(p.u1s, p.bf1, p.Wf2, p.bf2,
                                              p.dmh1, p.dmh2, p.acc);
  }
}